// Round 1
// baseline (457.111 us; speedup 1.0000x reference)
//
#include <hip/hip_runtime.h>
#include <math.h>

#define B_ 4
#define NA 1250
#define NP 50000
#define NE 125000
#define T_ 3
#define D_ 128
#define SHD 16
#define NB 10
#define HID 100
#define E_TOT (B_*NE)      // 500000
#define P_TOT (B_*NP)      // 200000
#define A_TOT (B_*NA)      // 5000
#define INV_SQRT_NN 0.22360679774997896f  // 1/sqrt(20)
#define SCAN_NBLK ((P_TOT + 1023) / 1024) // 196

// ---------------- edge kernel: geometry + SH + RB + MLP -> scal[e][3] ----------------
__global__ __launch_bounds__(256) void edge_kernel(
    const float* __restrict__ atom_xyz, const float* __restrict__ probe_xyz,
    const int* __restrict__ probe_edges, const float* __restrict__ ped,
    const float* __restrict__ cell, const float* __restrict__ w1,
    const float* __restrict__ w2,
    int* __restrict__ counts, int* __restrict__ rank,
    int* __restrict__ dstf, int* __restrict__ srcf, float* __restrict__ scal)
{
    __shared__ float sw1[T_*NB*HID];   // 3000 floats
    __shared__ float sw2[T_*HID*SHD];  // 4800 floats
    for (int i = threadIdx.x; i < T_*NB*HID;  i += 256) sw1[i] = w1[i];
    for (int i = threadIdx.x; i < T_*HID*SHD; i += 256) sw2[i] = w2[i];
    __syncthreads();

    int e = blockIdx.x * 256 + threadIdx.x;
    if (e >= E_TOT) return;
    int b  = e / NE;
    int le = e - b * NE;

    int sl = probe_edges[(size_t)b*NE*2 + (size_t)le*2 + 0];
    int dl = probe_edges[(size_t)b*NE*2 + (size_t)le*2 + 1];
    int src = sl + b * NA;   // flat atom index
    int dst = dl + b * NP;   // flat probe index

    float p0 = ped[(size_t)b*NE*3 + (size_t)le*3 + 0];
    float p1 = ped[(size_t)b*NE*3 + (size_t)le*3 + 1];
    float p2 = ped[(size_t)b*NE*3 + (size_t)le*3 + 2];
    const float* cb = cell + b*9;
    float dx = p0*cb[0] + p1*cb[3] + p2*cb[6];
    float dy = p0*cb[1] + p1*cb[4] + p2*cb[7];
    float dz = p0*cb[2] + p1*cb[5] + p2*cb[8];

    float vx = probe_xyz[(size_t)dst*3+0] - (atom_xyz[(size_t)src*3+0] + dx);
    float vy = probe_xyz[(size_t)dst*3+1] - (atom_xyz[(size_t)src*3+1] + dy);
    float vz = probe_xyz[(size_t)dst*3+2] - (atom_xyz[(size_t)src*3+2] + dz);
    float r = sqrtf(vx*vx + vy*vy + vz*vz);
    float rinv = 1.0f / fmaxf(r, 1e-9f);
    float x = vx*rinv, y = vy*rinv, z = vz*rinv;
    float x2 = x*x, y2 = y*y, z2 = z*z;

    const float S3  = 1.7320508075688772f;
    const float S15 = 3.872983346207417f;
    float sh[SHD];
    sh[0]  = 1.0f;
    sh[1]  = S3 * x;
    sh[2]  = S3 * y;
    sh[3]  = S3 * z;
    sh[4]  = S15 * x * y;
    sh[5]  = S15 * y * z;
    sh[6]  = 1.118033988749895f * (3.0f*z2 - 1.0f);
    sh[7]  = S15 * x * z;
    sh[8]  = 1.9364916731037085f * (x2 - y2);
    sh[9]  = 2.091650066335189f  * y * (3.0f*x2 - y2);
    sh[10] = 10.246950765959598f * x * y * z;
    sh[11] = 1.6201851746019651f * y * (5.0f*z2 - 1.0f);
    sh[12] = 1.3228756555322954f * (5.0f*z2*z - 3.0f*z);
    sh[13] = 1.6201851746019651f * x * (5.0f*z2 - 1.0f);
    sh[14] = 5.123475382979799f  * z * (x2 - y2);
    sh[15] = 2.091650066335189f  * x * (x2 - 3.0f*y2);

    // radial basis: centers i*(4/9), step 4/9
    float rb[NB];
    float rs = r * (9.0f / 4.0f);
    #pragma unroll
    for (int i = 0; i < NB; ++i) {
        float dif = rs - (float)i;
        rb[i] = __expf(-dif*dif) * 1.12f;
    }

    #pragma unroll
    for (int t = 0; t < T_; ++t) {
        const float* W1 = sw1 + t*NB*HID;
        const float* W2 = sw2 + t*HID*SHD;
        float acc = 0.0f;
        for (int j = 0; j < HID; ++j) {
            float h = 0.0f;
            #pragma unroll
            for (int i = 0; i < NB; ++i) h += rb[i] * W1[i*HID + j];
            float s = h / (1.0f + __expf(-h));   // silu
            float q = 0.0f;
            #pragma unroll
            for (int k = 0; k < SHD; ++k) q += W2[j*SHD + k] * sh[k];
            acc += s * q;
        }
        scal[(size_t)e*3 + t] = acc;
    }

    int rk = atomicAdd(&counts[dst], 1);
    rank[e] = rk;
    dstf[e] = dst;
    srcf[e] = src;
}

// ---------------- scan kernels (counting-sort CSR) ----------------
__global__ __launch_bounds__(256) void scan1_kernel(const int* __restrict__ counts,
                                                    int* __restrict__ starts,
                                                    int* __restrict__ bsums)
{
    __shared__ int sd[256];
    int base = blockIdx.x*1024 + threadIdx.x*4;
    int v0 = (base+0 < P_TOT) ? counts[base+0] : 0;
    int v1 = (base+1 < P_TOT) ? counts[base+1] : 0;
    int v2 = (base+2 < P_TOT) ? counts[base+2] : 0;
    int v3 = (base+3 < P_TOT) ? counts[base+3] : 0;
    int s = v0+v1+v2+v3;
    sd[threadIdx.x] = s;
    __syncthreads();
    for (int off = 1; off < 256; off <<= 1) {
        int t = (threadIdx.x >= off) ? sd[threadIdx.x - off] : 0;
        __syncthreads();
        sd[threadIdx.x] += t;
        __syncthreads();
    }
    int excl = sd[threadIdx.x] - s;
    if (base+0 < P_TOT) starts[base+0] = excl;
    if (base+1 < P_TOT) starts[base+1] = excl + v0;
    if (base+2 < P_TOT) starts[base+2] = excl + v0 + v1;
    if (base+3 < P_TOT) starts[base+3] = excl + v0 + v1 + v2;
    if (threadIdx.x == 255) bsums[blockIdx.x] = sd[255];
}

__global__ __launch_bounds__(256) void scan2_kernel(int* __restrict__ bsums, int n)
{
    __shared__ int sd[256];
    int s = (threadIdx.x < n) ? bsums[threadIdx.x] : 0;
    sd[threadIdx.x] = s;
    __syncthreads();
    for (int off = 1; off < 256; off <<= 1) {
        int t = (threadIdx.x >= off) ? sd[threadIdx.x - off] : 0;
        __syncthreads();
        sd[threadIdx.x] += t;
        __syncthreads();
    }
    if (threadIdx.x < n) bsums[threadIdx.x] = sd[threadIdx.x] - s;
}

__global__ __launch_bounds__(256) void scan3_kernel(int* __restrict__ starts,
                                                    const int* __restrict__ bsums)
{
    int add = bsums[blockIdx.x];
    int base = blockIdx.x*1024 + threadIdx.x*4;
    #pragma unroll
    for (int k = 0; k < 4; ++k)
        if (base+k < P_TOT) starts[base+k] += add;
}

__global__ __launch_bounds__(256) void scatter_kernel(const int* __restrict__ dstf,
                                                      const int* __restrict__ rank,
                                                      const int* __restrict__ starts,
                                                      int* __restrict__ edge_order)
{
    int e = blockIdx.x*256 + threadIdx.x;
    if (e >= E_TOT) return;
    edge_order[starts[dstf[e]] + rank[e]] = e;
}

// ---------------- gather: wave-per-probe accumulation, fused out projection ----------------
__global__ __launch_bounds__(256) void gather_kernel(
    const int* __restrict__ counts, const int* __restrict__ starts,
    const int* __restrict__ edge_order, const int* __restrict__ srcf,
    const float* __restrict__ scal, const float* __restrict__ atom_rep,
    const float* __restrict__ w_out,
    float* __restrict__ out, float* __restrict__ probes)
{
    int wave = threadIdx.x >> 6;
    int lane = threadIdx.x & 63;
    int p = blockIdx.x*4 + wave;   // P_TOT divisible by 4

    int st  = starts[p];
    int cnt = counts[p];
    float acc0 = 0.0f, acc1 = 0.0f;
    for (int i = 0; i < cnt; ++i) {
        int e = edge_order[st + i];
        int src = srcf[e];
        float s0 = scal[(size_t)e*3 + 0];
        float s1 = scal[(size_t)e*3 + 1];
        float s2 = scal[(size_t)e*3 + 2];
        const float* r0 = atom_rep + (size_t)src * D_;
        acc0 += s0*r0[lane]                  + s1*r0[(size_t)A_TOT*D_ + lane]
              + s2*r0[(size_t)2*A_TOT*D_ + lane];
        acc1 += s0*r0[lane+64]               + s1*r0[(size_t)A_TOT*D_ + lane+64]
              + s2*r0[(size_t)2*A_TOT*D_ + lane+64];
    }
    acc0 *= INV_SQRT_NN;
    acc1 *= INV_SQRT_NN;
    probes[(size_t)p*D_ + lane]      = acc0;
    probes[(size_t)p*D_ + lane + 64] = acc1;

    float ov = acc0*w_out[lane] + acc1*w_out[lane+64];
    #pragma unroll
    for (int off = 32; off > 0; off >>= 1) ov += __shfl_down(ov, off);
    if (lane == 0) out[p] = ov;
}

extern "C" void kernel_launch(void* const* d_in, const int* in_sizes, int n_in,
                              void* d_out, int out_size, void* d_ws, size_t ws_size,
                              hipStream_t stream) {
    const float* atom_xyz  = (const float*)d_in[0];
    const float* probe_xyz = (const float*)d_in[1];
    const int*   probe_edges = (const int*)d_in[2];
    const float* ped       = (const float*)d_in[3];
    const float* cell      = (const float*)d_in[4];
    const float* atom_rep  = (const float*)d_in[8];
    const float* w1        = (const float*)d_in[9];
    const float* w2        = (const float*)d_in[10];
    const float* w_out     = (const float*)d_in[11];

    float* out    = (float*)d_out;        // 200000 floats (B,NP)
    float* probes = out + P_TOT;          // 200000*128 floats

    int* counts     = (int*)d_ws;               // P_TOT
    int* starts     = counts + P_TOT;           // P_TOT
    int* bsums      = starts + P_TOT;           // 256
    int* rank       = bsums + 256;              // E_TOT
    int* dstf       = rank + E_TOT;             // E_TOT
    int* srcf       = dstf + E_TOT;             // E_TOT
    int* edge_order = srcf + E_TOT;             // E_TOT
    float* scal     = (float*)(edge_order + E_TOT); // E_TOT*3

    hipMemsetAsync(counts, 0, P_TOT*sizeof(int), stream);

    edge_kernel<<<(E_TOT + 255)/256, 256, 0, stream>>>(
        atom_xyz, probe_xyz, probe_edges, ped, cell, w1, w2,
        counts, rank, dstf, srcf, scal);

    scan1_kernel<<<SCAN_NBLK, 256, 0, stream>>>(counts, starts, bsums);
    scan2_kernel<<<1, 256, 0, stream>>>(bsums, SCAN_NBLK);
    scan3_kernel<<<SCAN_NBLK, 256, 0, stream>>>(starts, bsums);
    scatter_kernel<<<(E_TOT + 255)/256, 256, 0, stream>>>(dstf, rank, starts, edge_order);

    gather_kernel<<<P_TOT/4, 256, 0, stream>>>(
        counts, starts, edge_order, srcf, scal, atom_rep, w_out, out, probes);
}

// Round 2
// 385.880 us; speedup vs baseline: 1.1846x; 1.1846x over previous
//
#include <hip/hip_runtime.h>
#include <math.h>

#define B_ 4
#define NA 1250
#define NP 50000
#define NE 125000
#define T_ 3
#define D_ 128
#define SHD 16
#define NB 10
#define HID 100
#define E_TOT (B_*NE)      // 500000
#define P_TOT (B_*NP)      // 200000
#define A_TOT (B_*NA)      // 5000
#define INV_SQRT_NN 0.22360679774997896f  // 1/sqrt(20)
#define SCAN_NBLK ((P_TOT + 1023) / 1024) // 196
#define EPT 2                              // edges per thread in edge kernel

// ---------------- tiny pre-pass: transpose w1 [T][NB][HID] -> w1t [T][HID][NB] ----
__global__ __launch_bounds__(256) void transpose_w1_kernel(const float* __restrict__ w1,
                                                           float* __restrict__ w1t)
{
    int idx = blockIdx.x*256 + threadIdx.x;
    if (idx < T_*NB*HID) {
        int t = idx / (NB*HID);
        int r = idx - t*(NB*HID);
        int i = r / HID;
        int j = r - i*HID;
        w1t[(t*HID + j)*NB + i] = w1[idx];
    }
}

// ---------------- edge kernel: geometry + SH + RB + MLP -> scal[e][3] ----------------
// Weights read with wave-uniform indices from global -> scalar loads (s_load),
// zero VALU/LDS cost. 2 edges per thread for ILP + weight-load amortization.
__global__ __launch_bounds__(256) void edge_kernel(
    const float* __restrict__ atom_xyz, const float* __restrict__ probe_xyz,
    const int* __restrict__ probe_edges, const float* __restrict__ ped,
    const float* __restrict__ cell, const float* __restrict__ w1t,
    const float* __restrict__ w2,
    int* __restrict__ counts, int* __restrict__ rank,
    int* __restrict__ dstf, int* __restrict__ srcf, float* __restrict__ scal)
{
    int ebase = blockIdx.x * (256*EPT) + threadIdx.x;

    float rb[EPT][NB];
    float sh[EPT][SHD];
    int   eidx[EPT];

    #pragma unroll
    for (int u = 0; u < EPT; ++u) {
        int e = ebase + u*256;
        eidx[u] = e;
        int el = (e < E_TOT) ? e : (E_TOT-1);   // clamp loads, guard stores later
        int b  = el / NE;
        int le = el - b * NE;

        int sl = probe_edges[(size_t)b*NE*2 + (size_t)le*2 + 0];
        int dl = probe_edges[(size_t)b*NE*2 + (size_t)le*2 + 1];
        int src = sl + b * NA;
        int dst = dl + b * NP;

        float p0 = ped[(size_t)b*NE*3 + (size_t)le*3 + 0];
        float p1 = ped[(size_t)b*NE*3 + (size_t)le*3 + 1];
        float p2 = ped[(size_t)b*NE*3 + (size_t)le*3 + 2];
        const float* cb = cell + b*9;
        float dx = p0*cb[0] + p1*cb[3] + p2*cb[6];
        float dy = p0*cb[1] + p1*cb[4] + p2*cb[7];
        float dz = p0*cb[2] + p1*cb[5] + p2*cb[8];

        float vx = probe_xyz[(size_t)dst*3+0] - (atom_xyz[(size_t)src*3+0] + dx);
        float vy = probe_xyz[(size_t)dst*3+1] - (atom_xyz[(size_t)src*3+1] + dy);
        float vz = probe_xyz[(size_t)dst*3+2] - (atom_xyz[(size_t)src*3+2] + dz);
        float r = sqrtf(vx*vx + vy*vy + vz*vz);
        float rinv = 1.0f / fmaxf(r, 1e-9f);
        float x = vx*rinv, y = vy*rinv, z = vz*rinv;
        float x2 = x*x, y2 = y*y, z2 = z*z;

        const float S3  = 1.7320508075688772f;
        const float S15 = 3.872983346207417f;
        sh[u][0]  = 1.0f;
        sh[u][1]  = S3 * x;
        sh[u][2]  = S3 * y;
        sh[u][3]  = S3 * z;
        sh[u][4]  = S15 * x * y;
        sh[u][5]  = S15 * y * z;
        sh[u][6]  = 1.118033988749895f * (3.0f*z2 - 1.0f);
        sh[u][7]  = S15 * x * z;
        sh[u][8]  = 1.9364916731037085f * (x2 - y2);
        sh[u][9]  = 2.091650066335189f  * y * (3.0f*x2 - y2);
        sh[u][10] = 10.246950765959598f * x * y * z;
        sh[u][11] = 1.6201851746019651f * y * (5.0f*z2 - 1.0f);
        sh[u][12] = 1.3228756555322954f * (5.0f*z2*z - 3.0f*z);
        sh[u][13] = 1.6201851746019651f * x * (5.0f*z2 - 1.0f);
        sh[u][14] = 5.123475382979799f  * z * (x2 - y2);
        sh[u][15] = 2.091650066335189f  * x * (x2 - 3.0f*y2);

        float rs = r * (9.0f / 4.0f);
        #pragma unroll
        for (int i = 0; i < NB; ++i) {
            float dif = rs - (float)i;
            rb[u][i] = __expf(-dif*dif) * 1.12f;
        }

        if (e < E_TOT) {
            int rk = atomicAdd(&counts[dst], 1);
            rank[e] = rk;
            dstf[e] = dst;
            srcf[e] = src;
        }
    }

    // MLP: uniform weight access -> scalar loads
    #pragma unroll
    for (int t = 0; t < T_; ++t) {
        float acc[EPT];
        #pragma unroll
        for (int u = 0; u < EPT; ++u) acc[u] = 0.0f;

        for (int j = 0; j < HID; ++j) {
            const float* c1 = w1t + (t*HID + j)*NB;   // 10 contiguous floats
            const float* c2 = w2  + (t*HID + j)*SHD;  // 16 contiguous floats
            float h[EPT];
            #pragma unroll
            for (int u = 0; u < EPT; ++u) h[u] = 0.0f;
            #pragma unroll
            for (int i = 0; i < NB; ++i) {
                float w = c1[i];
                #pragma unroll
                for (int u = 0; u < EPT; ++u) h[u] += rb[u][i] * w;
            }
            float s[EPT];
            #pragma unroll
            for (int u = 0; u < EPT; ++u)
                s[u] = h[u] * __builtin_amdgcn_rcpf(1.0f + __expf(-h[u]));
            float q[EPT];
            #pragma unroll
            for (int u = 0; u < EPT; ++u) q[u] = 0.0f;
            #pragma unroll
            for (int k = 0; k < SHD; ++k) {
                float w = c2[k];
                #pragma unroll
                for (int u = 0; u < EPT; ++u) q[u] += w * sh[u][k];
            }
            #pragma unroll
            for (int u = 0; u < EPT; ++u) acc[u] += s[u] * q[u];
        }

        #pragma unroll
        for (int u = 0; u < EPT; ++u)
            if (eidx[u] < E_TOT) scal[(size_t)eidx[u]*3 + t] = acc[u];
    }
}

// ---------------- scan kernels (counting-sort CSR) ----------------
__global__ __launch_bounds__(256) void scan1_kernel(const int* __restrict__ counts,
                                                    int* __restrict__ starts,
                                                    int* __restrict__ bsums)
{
    __shared__ int sd[256];
    int base = blockIdx.x*1024 + threadIdx.x*4;
    int v0 = (base+0 < P_TOT) ? counts[base+0] : 0;
    int v1 = (base+1 < P_TOT) ? counts[base+1] : 0;
    int v2 = (base+2 < P_TOT) ? counts[base+2] : 0;
    int v3 = (base+3 < P_TOT) ? counts[base+3] : 0;
    int s = v0+v1+v2+v3;
    sd[threadIdx.x] = s;
    __syncthreads();
    for (int off = 1; off < 256; off <<= 1) {
        int t = (threadIdx.x >= off) ? sd[threadIdx.x - off] : 0;
        __syncthreads();
        sd[threadIdx.x] += t;
        __syncthreads();
    }
    int excl = sd[threadIdx.x] - s;
    if (base+0 < P_TOT) starts[base+0] = excl;
    if (base+1 < P_TOT) starts[base+1] = excl + v0;
    if (base+2 < P_TOT) starts[base+2] = excl + v0 + v1;
    if (base+3 < P_TOT) starts[base+3] = excl + v0 + v1 + v2;
    if (threadIdx.x == 255) bsums[blockIdx.x] = sd[255];
}

__global__ __launch_bounds__(256) void scan2_kernel(int* __restrict__ bsums, int n)
{
    __shared__ int sd[256];
    int s = (threadIdx.x < n) ? bsums[threadIdx.x] : 0;
    sd[threadIdx.x] = s;
    __syncthreads();
    for (int off = 1; off < 256; off <<= 1) {
        int t = (threadIdx.x >= off) ? sd[threadIdx.x - off] : 0;
        __syncthreads();
        sd[threadIdx.x] += t;
        __syncthreads();
    }
    if (threadIdx.x < n) bsums[threadIdx.x] = sd[threadIdx.x] - s;
}

__global__ __launch_bounds__(256) void scan3_kernel(int* __restrict__ starts,
                                                    const int* __restrict__ bsums)
{
    int add = bsums[blockIdx.x];
    int base = blockIdx.x*1024 + threadIdx.x*4;
    #pragma unroll
    for (int k = 0; k < 4; ++k)
        if (base+k < P_TOT) starts[base+k] += add;
}

__global__ __launch_bounds__(256) void scatter_kernel(const int* __restrict__ dstf,
                                                      const int* __restrict__ rank,
                                                      const int* __restrict__ starts,
                                                      int* __restrict__ edge_order)
{
    int e = blockIdx.x*256 + threadIdx.x;
    if (e >= E_TOT) return;
    edge_order[starts[dstf[e]] + rank[e]] = e;
}

// ---------------- gather: wave-per-probe accumulation, fused out projection ----------------
__global__ __launch_bounds__(256) void gather_kernel(
    const int* __restrict__ counts, const int* __restrict__ starts,
    const int* __restrict__ edge_order, const int* __restrict__ srcf,
    const float* __restrict__ scal, const float* __restrict__ atom_rep,
    const float* __restrict__ w_out,
    float* __restrict__ out, float* __restrict__ probes)
{
    int wave = threadIdx.x >> 6;
    int lane = threadIdx.x & 63;
    int p = blockIdx.x*4 + wave;   // P_TOT divisible by 4

    int st  = starts[p];
    int cnt = counts[p];
    const float2* rep2 = (const float2*)atom_rep;
    const size_t TSTRIDE = (size_t)A_TOT * (D_/2);   // float2 elems per t-slab

    float ax = 0.0f, ay = 0.0f;
    for (int i = 0; i < cnt; ++i) {
        int e = edge_order[st + i];
        int src = srcf[e];
        float s0 = scal[(size_t)e*3 + 0];
        float s1 = scal[(size_t)e*3 + 1];
        float s2 = scal[(size_t)e*3 + 2];
        size_t ro = (size_t)src * (D_/2) + lane;
        float2 a0 = rep2[ro];
        float2 a1 = rep2[TSTRIDE + ro];
        float2 a2 = rep2[2*TSTRIDE + ro];
        ax += s0*a0.x + s1*a1.x + s2*a2.x;
        ay += s0*a0.y + s1*a1.y + s2*a2.y;
    }
    ax *= INV_SQRT_NN;
    ay *= INV_SQRT_NN;
    ((float2*)probes)[(size_t)p*(D_/2) + lane] = make_float2(ax, ay);

    float ov = ax*w_out[2*lane] + ay*w_out[2*lane+1];
    #pragma unroll
    for (int off = 32; off > 0; off >>= 1) ov += __shfl_down(ov, off);
    if (lane == 0) out[p] = ov;
}

extern "C" void kernel_launch(void* const* d_in, const int* in_sizes, int n_in,
                              void* d_out, int out_size, void* d_ws, size_t ws_size,
                              hipStream_t stream) {
    const float* atom_xyz  = (const float*)d_in[0];
    const float* probe_xyz = (const float*)d_in[1];
    const int*   probe_edges = (const int*)d_in[2];
    const float* ped       = (const float*)d_in[3];
    const float* cell      = (const float*)d_in[4];
    const float* atom_rep  = (const float*)d_in[8];
    const float* w1        = (const float*)d_in[9];
    const float* w2        = (const float*)d_in[10];
    const float* w_out     = (const float*)d_in[11];

    float* out    = (float*)d_out;        // 200000 floats (B,NP)
    float* probes = out + P_TOT;          // 200000*128 floats

    int* counts     = (int*)d_ws;               // P_TOT
    int* starts     = counts + P_TOT;           // P_TOT
    int* bsums      = starts + P_TOT;           // 256
    int* rank       = bsums + 256;              // E_TOT
    int* dstf       = rank + E_TOT;             // E_TOT
    int* srcf       = dstf + E_TOT;             // E_TOT
    int* edge_order = srcf + E_TOT;             // E_TOT
    float* scal     = (float*)(edge_order + E_TOT); // E_TOT*3
    float* w1t      = scal + (size_t)E_TOT*3;       // T_*NB*HID

    hipMemsetAsync(counts, 0, P_TOT*sizeof(int), stream);

    transpose_w1_kernel<<<(T_*NB*HID + 255)/256, 256, 0, stream>>>(w1, w1t);

    edge_kernel<<<(E_TOT + 256*EPT - 1)/(256*EPT), 256, 0, stream>>>(
        atom_xyz, probe_xyz, probe_edges, ped, cell, w1t, w2,
        counts, rank, dstf, srcf, scal);

    scan1_kernel<<<SCAN_NBLK, 256, 0, stream>>>(counts, starts, bsums);
    scan2_kernel<<<1, 256, 0, stream>>>(bsums, SCAN_NBLK);
    scan3_kernel<<<SCAN_NBLK, 256, 0, stream>>>(starts, bsums);
    scatter_kernel<<<(E_TOT + 255)/256, 256, 0, stream>>>(dstf, rank, starts, edge_order);

    gather_kernel<<<P_TOT/4, 256, 0, stream>>>(
        counts, starts, edge_order, srcf, scal, atom_rep, w_out, out, probes);
}

// Round 4
// 325.030 us; speedup vs baseline: 1.4064x; 1.1872x over previous
//
#include <hip/hip_runtime.h>
#include <math.h>

#define B_ 4
#define NA 1250
#define NP 50000
#define NE 125000
#define T_ 3
#define D_ 128
#define SHD 16
#define NB 10
#define HID 100
#define E_TOT (B_*NE)      // 500000
#define P_TOT (B_*NP)      // 200000
#define A_TOT (B_*NA)      // 5000
#define INV_SQRT_NN 0.22360679774997896f  // 1/sqrt(20)
#define SCAN_NBLK ((P_TOT + 1023) / 1024) // 196

#define GRID_N 8192
#define RMAX 24.0f
#define FSTR (T_*SHD)      // 48 floats per table row

// ---------------- build radial table: ftab[r][t*16+k] = f_{t,k}(r) ----------------
// f_{t,k}(r) = (silu(rb(r) @ W1_t) @ W2_t)_k  -- function of scalar r only.
__global__ __launch_bounds__(256) void build_table_kernel(
    const float* __restrict__ w1, const float* __restrict__ w2,
    float* __restrict__ ftab)
{
    int idx = blockIdx.x*256 + threadIdx.x;
    if (idx >= T_*GRID_N) return;
    int t = idx >> 13;            // idx / GRID_N  (wave-uniform: GRID_N % 64 == 0)
    int ri = idx & (GRID_N-1);

    float r = (float)ri * (RMAX / (float)(GRID_N-1));
    float rb[NB];
    float rs = r * (9.0f / 4.0f);
    #pragma unroll
    for (int i = 0; i < NB; ++i) {
        float dif = rs - (float)i;
        rb[i] = __expf(-dif*dif) * 1.12f;
    }

    float fk[SHD];
    #pragma unroll
    for (int k = 0; k < SHD; ++k) fk[k] = 0.0f;

    for (int j = 0; j < HID; ++j) {
        float h = 0.0f;
        #pragma unroll
        for (int i = 0; i < NB; ++i)
            h += rb[i] * w1[(size_t)(t*NB + i)*HID + j];   // uniform -> s_load
        float s = h / (1.0f + __expf(-h));                 // silu
        #pragma unroll
        for (int k = 0; k < SHD; ++k)
            fk[k] += s * w2[(size_t)(t*HID + j)*SHD + k];
    }

    float* dstp = ftab + (size_t)ri*FSTR + t*SHD;
    #pragma unroll
    for (int k = 0; k < SHD; ++k) dstp[k] = fk[k];
}

// ---------------- edge kernel: geometry + SH + table interp -> scal[e][3] ----------------
__global__ __launch_bounds__(256) void edge_kernel(
    const float* __restrict__ atom_xyz, const float* __restrict__ probe_xyz,
    const int* __restrict__ probe_edges, const float* __restrict__ ped,
    const float* __restrict__ cell, const float* __restrict__ ftab,
    int* __restrict__ counts, int* __restrict__ rank,
    int* __restrict__ dstf, int* __restrict__ srcf, float* __restrict__ scal)
{
    int e = blockIdx.x * 256 + threadIdx.x;
    if (e >= E_TOT) return;
    int b  = e / NE;
    int le = e - b * NE;

    int sl = probe_edges[(size_t)b*NE*2 + (size_t)le*2 + 0];
    int dl = probe_edges[(size_t)b*NE*2 + (size_t)le*2 + 1];
    int src = sl + b * NA;
    int dst = dl + b * NP;

    float p0 = ped[(size_t)b*NE*3 + (size_t)le*3 + 0];
    float p1 = ped[(size_t)b*NE*3 + (size_t)le*3 + 1];
    float p2 = ped[(size_t)b*NE*3 + (size_t)le*3 + 2];
    const float* cb = cell + b*9;
    float dx = p0*cb[0] + p1*cb[3] + p2*cb[6];
    float dy = p0*cb[1] + p1*cb[4] + p2*cb[7];
    float dz = p0*cb[2] + p1*cb[5] + p2*cb[8];

    float vx = probe_xyz[(size_t)dst*3+0] - (atom_xyz[(size_t)src*3+0] + dx);
    float vy = probe_xyz[(size_t)dst*3+1] - (atom_xyz[(size_t)src*3+1] + dy);
    float vz = probe_xyz[(size_t)dst*3+2] - (atom_xyz[(size_t)src*3+2] + dz);
    float r = sqrtf(vx*vx + vy*vy + vz*vz);
    float rinv = 1.0f / fmaxf(r, 1e-9f);
    float x = vx*rinv, y = vy*rinv, z = vz*rinv;
    float x2 = x*x, y2 = y*y, z2 = z*z;

    const float S3  = 1.7320508075688772f;
    const float S15 = 3.872983346207417f;
    float sh[SHD];
    sh[0]  = 1.0f;
    sh[1]  = S3 * x;
    sh[2]  = S3 * y;
    sh[3]  = S3 * z;
    sh[4]  = S15 * x * y;
    sh[5]  = S15 * y * z;
    sh[6]  = 1.118033988749895f * (3.0f*z2 - 1.0f);
    sh[7]  = S15 * x * z;
    sh[8]  = 1.9364916731037085f * (x2 - y2);
    sh[9]  = 2.091650066335189f  * y * (3.0f*x2 - y2);
    sh[10] = 10.246950765959598f * x * y * z;
    sh[11] = 1.6201851746019651f * y * (5.0f*z2 - 1.0f);
    sh[12] = 1.3228756555322954f * (5.0f*z2*z - 3.0f*z);
    sh[13] = 1.6201851746019651f * x * (5.0f*z2 - 1.0f);
    sh[14] = 5.123475382979799f  * z * (x2 - y2);
    sh[15] = 2.091650066335189f  * x * (x2 - 3.0f*y2);

    // table interpolation
    float u = r * ((float)(GRID_N-1) / RMAX);
    int i0 = (int)u;
    i0 = (i0 > GRID_N-2) ? (GRID_N-2) : i0;
    float w = u - (float)i0;
    const float* F0 = ftab + (size_t)i0 * FSTR;
    const float* F1 = F0 + FSTR;

    #pragma unroll
    for (int t = 0; t < T_; ++t) {
        float d0 = 0.0f, d1 = 0.0f;
        #pragma unroll
        for (int k = 0; k < SHD; ++k) {
            d0 += F0[t*SHD + k] * sh[k];
            d1 += F1[t*SHD + k] * sh[k];
        }
        scal[(size_t)e*3 + t] = d0 + w * (d1 - d0);
    }

    int rk = atomicAdd(&counts[dst], 1);
    rank[e] = rk;
    dstf[e] = dst;
    srcf[e] = src;
}

// ---------------- scan kernels (counting-sort CSR) ----------------
__global__ __launch_bounds__(256) void scan1_kernel(const int* __restrict__ counts,
                                                    int* __restrict__ starts,
                                                    int* __restrict__ bsums)
{
    __shared__ int sd[256];
    int base = blockIdx.x*1024 + threadIdx.x*4;
    int v0 = (base+0 < P_TOT) ? counts[base+0] : 0;
    int v1 = (base+1 < P_TOT) ? counts[base+1] : 0;
    int v2 = (base+2 < P_TOT) ? counts[base+2] : 0;
    int v3 = (base+3 < P_TOT) ? counts[base+3] : 0;
    int s = v0+v1+v2+v3;
    sd[threadIdx.x] = s;
    __syncthreads();
    for (int off = 1; off < 256; off <<= 1) {
        int t = (threadIdx.x >= off) ? sd[threadIdx.x - off] : 0;
        __syncthreads();
        sd[threadIdx.x] += t;
        __syncthreads();
    }
    int excl = sd[threadIdx.x] - s;
    if (base+0 < P_TOT) starts[base+0] = excl;
    if (base+1 < P_TOT) starts[base+1] = excl + v0;
    if (base+2 < P_TOT) starts[base+2] = excl + v0 + v1;
    if (base+3 < P_TOT) starts[base+3] = excl + v0 + v1 + v2;
    if (threadIdx.x == 255) bsums[blockIdx.x] = sd[255];
}

__global__ __launch_bounds__(256) void scan2_kernel(int* __restrict__ bsums, int n)
{
    __shared__ int sd[256];
    int s = (threadIdx.x < n) ? bsums[threadIdx.x] : 0;
    sd[threadIdx.x] = s;
    __syncthreads();
    for (int off = 1; off < 256; off <<= 1) {
        int t = (threadIdx.x >= off) ? sd[threadIdx.x - off] : 0;
        __syncthreads();
        sd[threadIdx.x] += t;
        __syncthreads();
    }
    if (threadIdx.x < n) bsums[threadIdx.x] = sd[threadIdx.x] - s;
}

__global__ __launch_bounds__(256) void scan3_kernel(int* __restrict__ starts,
                                                    const int* __restrict__ bsums)
{
    int add = bsums[blockIdx.x];
    int base = blockIdx.x*1024 + threadIdx.x*4;
    #pragma unroll
    for (int k = 0; k < 4; ++k)
        if (base+k < P_TOT) starts[base+k] += add;
}

// ---------------- scatter: materialize src + scal in CSR order ----------------
__global__ __launch_bounds__(256) void scatter_kernel(const int* __restrict__ dstf,
                                                      const int* __restrict__ rank,
                                                      const int* __restrict__ starts,
                                                      const int* __restrict__ srcf,
                                                      const float* __restrict__ scal,
                                                      int* __restrict__ srcf_s,
                                                      float* __restrict__ scal_s)
{
    int e = blockIdx.x*256 + threadIdx.x;
    if (e >= E_TOT) return;
    int pos = starts[dstf[e]] + rank[e];
    srcf_s[pos] = srcf[e];
    float s0 = scal[(size_t)e*3+0];
    float s1 = scal[(size_t)e*3+1];
    float s2 = scal[(size_t)e*3+2];
    scal_s[(size_t)pos*3+0] = s0;
    scal_s[(size_t)pos*3+1] = s1;
    scal_s[(size_t)pos*3+2] = s2;
}

// ---------------- gather: wave-per-probe accumulation, fused out projection ----------------
__global__ __launch_bounds__(256) void gather_kernel(
    const int* __restrict__ counts, const int* __restrict__ starts,
    const int* __restrict__ srcf_s, const float* __restrict__ scal_s,
    const float* __restrict__ atom_rep, const float* __restrict__ w_out,
    float* __restrict__ out, float* __restrict__ probes)
{
    int wave = threadIdx.x >> 6;
    int lane = threadIdx.x & 63;
    int p = blockIdx.x*4 + wave;   // P_TOT divisible by 4

    int st  = starts[p];
    int cnt = counts[p];
    const float2* rep2 = (const float2*)atom_rep;
    const size_t TSTRIDE = (size_t)A_TOT * (D_/2);   // float2 elems per t-slab

    float ax = 0.0f, ay = 0.0f;
    for (int i = 0; i < cnt; ++i) {
        int src = srcf_s[st + i];
        float s0 = scal_s[(size_t)(st+i)*3 + 0];
        float s1 = scal_s[(size_t)(st+i)*3 + 1];
        float s2 = scal_s[(size_t)(st+i)*3 + 2];
        size_t ro = (size_t)src * (D_/2) + lane;
        float2 a0 = rep2[ro];
        float2 a1 = rep2[TSTRIDE + ro];
        float2 a2 = rep2[2*TSTRIDE + ro];
        ax += s0*a0.x + s1*a1.x + s2*a2.x;
        ay += s0*a0.y + s1*a1.y + s2*a2.y;
    }
    ax *= INV_SQRT_NN;
    ay *= INV_SQRT_NN;
    ((float2*)probes)[(size_t)p*(D_/2) + lane] = make_float2(ax, ay);

    float ov = ax*w_out[2*lane] + ay*w_out[2*lane+1];
    #pragma unroll
    for (int off = 32; off > 0; off >>= 1) ov += __shfl_down(ov, off);
    if (lane == 0) out[p] = ov;
}

extern "C" void kernel_launch(void* const* d_in, const int* in_sizes, int n_in,
                              void* d_out, int out_size, void* d_ws, size_t ws_size,
                              hipStream_t stream) {
    const float* atom_xyz  = (const float*)d_in[0];
    const float* probe_xyz = (const float*)d_in[1];
    const int*   probe_edges = (const int*)d_in[2];
    const float* ped       = (const float*)d_in[3];
    const float* cell      = (const float*)d_in[4];
    const float* atom_rep  = (const float*)d_in[8];
    const float* w1        = (const float*)d_in[9];
    const float* w2        = (const float*)d_in[10];
    const float* w_out     = (const float*)d_in[11];

    float* out    = (float*)d_out;        // 200000 floats (B,NP)
    float* probes = out + P_TOT;          // 200000*128 floats

    int* counts     = (int*)d_ws;                 // P_TOT
    int* starts     = counts + P_TOT;             // P_TOT
    int* bsums      = starts + P_TOT;             // 256
    int* rank       = bsums + 256;                // E_TOT
    int* dstf       = rank + E_TOT;               // E_TOT
    int* srcf       = dstf + E_TOT;               // E_TOT
    int* srcf_s     = srcf + E_TOT;               // E_TOT
    float* scal     = (float*)(srcf_s + E_TOT);   // E_TOT*3
    float* scal_s   = scal + (size_t)E_TOT*3;     // E_TOT*3
    float* ftab     = scal_s + (size_t)E_TOT*3;   // GRID_N*48

    hipMemsetAsync(counts, 0, P_TOT*sizeof(int), stream);

    build_table_kernel<<<(T_*GRID_N + 255)/256, 256, 0, stream>>>(w1, w2, ftab);

    edge_kernel<<<(E_TOT + 255)/256, 256, 0, stream>>>(
        atom_xyz, probe_xyz, probe_edges, ped, cell, ftab,
        counts, rank, dstf, srcf, scal);

    scan1_kernel<<<SCAN_NBLK, 256, 0, stream>>>(counts, starts, bsums);
    scan2_kernel<<<1, 256, 0, stream>>>(bsums, SCAN_NBLK);
    scan3_kernel<<<SCAN_NBLK, 256, 0, stream>>>(starts, bsums);
    scatter_kernel<<<(E_TOT + 255)/256, 256, 0, stream>>>(
        dstf, rank, starts, srcf, scal, srcf_s, scal_s);

    gather_kernel<<<P_TOT/4, 256, 0, stream>>>(
        counts, starts, srcf_s, scal_s, atom_rep, w_out, out, probes);
}

// Round 5
// 306.094 us; speedup vs baseline: 1.4934x; 1.0619x over previous
//
#include <hip/hip_runtime.h>
#include <math.h>

#define B_ 4
#define NA 1250
#define NP 50000
#define NE 125000
#define T_ 3
#define D_ 128
#define SHD 16
#define NB 10
#define HID 100
#define E_TOT (B_*NE)      // 500000
#define P_TOT (B_*NP)      // 200000
#define A_TOT (B_*NA)      // 5000
#define INV_SQRT_NN 0.22360679774997896f  // 1/sqrt(20)
#define SCAN_NBLK ((P_TOT + 1023) / 1024) // 196

#define GRID_N 8192
#define RMAX 24.0f
#define FSTR (T_*SHD)      // 48 floats per table row

typedef float f32x2 __attribute__((ext_vector_type(2)));

// ---------------- build radial table: ftab[r][t*16+k] = f_{t,k}(r) ----------------
__global__ __launch_bounds__(256) void build_table_kernel(
    const float* __restrict__ w1, const float* __restrict__ w2,
    float* __restrict__ ftab)
{
    int idx = blockIdx.x*256 + threadIdx.x;
    if (idx >= T_*GRID_N) return;
    int t = idx >> 13;            // idx / GRID_N  (wave-uniform: GRID_N % 64 == 0)
    int ri = idx & (GRID_N-1);

    float r = (float)ri * (RMAX / (float)(GRID_N-1));
    float rb[NB];
    float rs = r * (9.0f / 4.0f);
    #pragma unroll
    for (int i = 0; i < NB; ++i) {
        float dif = rs - (float)i;
        rb[i] = __expf(-dif*dif) * 1.12f;
    }

    float fk[SHD];
    #pragma unroll
    for (int k = 0; k < SHD; ++k) fk[k] = 0.0f;

    for (int j = 0; j < HID; ++j) {
        float h = 0.0f;
        #pragma unroll
        for (int i = 0; i < NB; ++i)
            h += rb[i] * w1[(size_t)(t*NB + i)*HID + j];   // uniform -> s_load
        float s = h / (1.0f + __expf(-h));                 // silu
        #pragma unroll
        for (int k = 0; k < SHD; ++k)
            fk[k] += s * w2[(size_t)(t*HID + j)*SHD + k];
    }

    float* dstp = ftab + (size_t)ri*FSTR + t*SHD;
    #pragma unroll
    for (int k = 0; k < SHD; ++k) dstp[k] = fk[k];
}

// ---------------- count: histogram of dst ----------------
__global__ __launch_bounds__(256) void count_kernel(const int* __restrict__ probe_edges,
                                                    int* __restrict__ counts)
{
    int e = blockIdx.x*256 + threadIdx.x;
    if (e >= E_TOT) return;
    int b = e / NE;
    int dl = probe_edges[(size_t)e*2 + 1];
    atomicAdd(&counts[dl + b*NP], 1);
}

// ---------------- scan kernels (counting-sort CSR) ----------------
__global__ __launch_bounds__(256) void scan1_kernel(const int* __restrict__ counts,
                                                    int* __restrict__ starts,
                                                    int* __restrict__ bsums)
{
    __shared__ int sd[256];
    int base = blockIdx.x*1024 + threadIdx.x*4;
    int v0 = (base+0 < P_TOT) ? counts[base+0] : 0;
    int v1 = (base+1 < P_TOT) ? counts[base+1] : 0;
    int v2 = (base+2 < P_TOT) ? counts[base+2] : 0;
    int v3 = (base+3 < P_TOT) ? counts[base+3] : 0;
    int s = v0+v1+v2+v3;
    sd[threadIdx.x] = s;
    __syncthreads();
    for (int off = 1; off < 256; off <<= 1) {
        int t = (threadIdx.x >= off) ? sd[threadIdx.x - off] : 0;
        __syncthreads();
        sd[threadIdx.x] += t;
        __syncthreads();
    }
    int excl = sd[threadIdx.x] - s;
    if (base+0 < P_TOT) starts[base+0] = excl;
    if (base+1 < P_TOT) starts[base+1] = excl + v0;
    if (base+2 < P_TOT) starts[base+2] = excl + v0 + v1;
    if (base+3 < P_TOT) starts[base+3] = excl + v0 + v1 + v2;
    if (threadIdx.x == 255) bsums[blockIdx.x] = sd[255];
}

__global__ __launch_bounds__(256) void scan2_kernel(int* __restrict__ bsums, int n)
{
    __shared__ int sd[256];
    int s = (threadIdx.x < n) ? bsums[threadIdx.x] : 0;
    sd[threadIdx.x] = s;
    __syncthreads();
    for (int off = 1; off < 256; off <<= 1) {
        int t = (threadIdx.x >= off) ? sd[threadIdx.x - off] : 0;
        __syncthreads();
        sd[threadIdx.x] += t;
        __syncthreads();
    }
    if (threadIdx.x < n) bsums[threadIdx.x] = sd[threadIdx.x] - s;
}

__global__ __launch_bounds__(256) void scan3_kernel(int* __restrict__ starts,
                                                    const int* __restrict__ bsums)
{
    int add = bsums[blockIdx.x];
    int base = blockIdx.x*1024 + threadIdx.x*4;
    #pragma unroll
    for (int k = 0; k < 4; ++k)
        if (base+k < P_TOT) starts[base+k] += add;
}

// ---------------- edge_scatter: geometry + SH + interp -> CSR slot {s0,s1,s2,src} ----
__global__ __launch_bounds__(256) void edge_scatter_kernel(
    const float* __restrict__ atom_xyz, const float* __restrict__ probe_xyz,
    const int* __restrict__ probe_edges, const float* __restrict__ ped,
    const float* __restrict__ cell, const float* __restrict__ ftab,
    const int* __restrict__ starts, int* __restrict__ counts2,
    float4* __restrict__ edge4)
{
    int e = blockIdx.x * 256 + threadIdx.x;
    if (e >= E_TOT) return;
    int b  = e / NE;

    int sl = probe_edges[(size_t)e*2 + 0];
    int dl = probe_edges[(size_t)e*2 + 1];
    int src = sl + b * NA;
    int dst = dl + b * NP;

    float p0 = ped[(size_t)e*3 + 0];
    float p1 = ped[(size_t)e*3 + 1];
    float p2 = ped[(size_t)e*3 + 2];
    const float* cb = cell + b*9;
    float dx = p0*cb[0] + p1*cb[3] + p2*cb[6];
    float dy = p0*cb[1] + p1*cb[4] + p2*cb[7];
    float dz = p0*cb[2] + p1*cb[5] + p2*cb[8];

    float vx = probe_xyz[(size_t)dst*3+0] - (atom_xyz[(size_t)src*3+0] + dx);
    float vy = probe_xyz[(size_t)dst*3+1] - (atom_xyz[(size_t)src*3+1] + dy);
    float vz = probe_xyz[(size_t)dst*3+2] - (atom_xyz[(size_t)src*3+2] + dz);
    float r = sqrtf(vx*vx + vy*vy + vz*vz);
    float rinv = 1.0f / fmaxf(r, 1e-9f);
    float x = vx*rinv, y = vy*rinv, z = vz*rinv;
    float x2 = x*x, y2 = y*y, z2 = z*z;

    const float S3  = 1.7320508075688772f;
    const float S15 = 3.872983346207417f;
    float sh[SHD];
    sh[0]  = 1.0f;
    sh[1]  = S3 * x;
    sh[2]  = S3 * y;
    sh[3]  = S3 * z;
    sh[4]  = S15 * x * y;
    sh[5]  = S15 * y * z;
    sh[6]  = 1.118033988749895f * (3.0f*z2 - 1.0f);
    sh[7]  = S15 * x * z;
    sh[8]  = 1.9364916731037085f * (x2 - y2);
    sh[9]  = 2.091650066335189f  * y * (3.0f*x2 - y2);
    sh[10] = 10.246950765959598f * x * y * z;
    sh[11] = 1.6201851746019651f * y * (5.0f*z2 - 1.0f);
    sh[12] = 1.3228756555322954f * (5.0f*z2*z - 3.0f*z);
    sh[13] = 1.6201851746019651f * x * (5.0f*z2 - 1.0f);
    sh[14] = 5.123475382979799f  * z * (x2 - y2);
    sh[15] = 2.091650066335189f  * x * (x2 - 3.0f*y2);

    // table interpolation
    float u = r * ((float)(GRID_N-1) / RMAX);
    int i0 = (int)u;
    i0 = (i0 > GRID_N-2) ? (GRID_N-2) : i0;
    float w = u - (float)i0;
    const float* F0 = ftab + (size_t)i0 * FSTR;
    const float* F1 = F0 + FSTR;

    float sc[T_];
    #pragma unroll
    for (int t = 0; t < T_; ++t) {
        float d0 = 0.0f, d1 = 0.0f;
        #pragma unroll
        for (int k = 0; k < SHD; ++k) {
            d0 += F0[t*SHD + k] * sh[k];
            d1 += F1[t*SHD + k] * sh[k];
        }
        sc[t] = d0 + w * (d1 - d0);
    }

    int pos = starts[dst] + atomicAdd(&counts2[dst], 1);
    edge4[pos] = make_float4(sc[0], sc[1], sc[2], __int_as_float(src));
}

// ---------------- gather: wave-per-probe, unrolled chunk-of-4, fused projection ------
__global__ __launch_bounds__(256) void gather_kernel(
    const int* __restrict__ counts, const int* __restrict__ starts,
    const float4* __restrict__ edge4, const float* __restrict__ atom_rep,
    const float* __restrict__ w_out,
    float* __restrict__ out, float* __restrict__ probes)
{
    int lane = threadIdx.x & 63;
    int wv   = threadIdx.x >> 6;
    int p = blockIdx.x*4 + wv;   // P_TOT divisible by 4

    int st  = __builtin_amdgcn_readfirstlane(starts[p]);
    int cnt = __builtin_amdgcn_readfirstlane(counts[p]);

    const float2* rep2 = (const float2*)atom_rep;
    const size_t TS = (size_t)A_TOT * (D_/2);   // float2 elems per t-slab

    float ax = 0.0f, ay = 0.0f;

    for (int base = 0; base < cnt; base += 4) {
        int m = cnt - base;                 // wave-uniform
        float4 e0, e1, e2, e3;
        e0 = edge4[st+base];
        if (m > 1) e1 = edge4[st+base+1];
        if (m > 2) e2 = edge4[st+base+2];
        if (m > 3) e3 = edge4[st+base+3];

        float2 a00,a01,a02, a10,a11,a12, a20,a21,a22, a30,a31,a32;
        {           size_t ro = (size_t)__float_as_int(e0.w)*(D_/2) + lane;
                    a00 = rep2[ro]; a01 = rep2[TS+ro]; a02 = rep2[2*TS+ro]; }
        if (m > 1) { size_t ro = (size_t)__float_as_int(e1.w)*(D_/2) + lane;
                    a10 = rep2[ro]; a11 = rep2[TS+ro]; a12 = rep2[2*TS+ro]; }
        if (m > 2) { size_t ro = (size_t)__float_as_int(e2.w)*(D_/2) + lane;
                    a20 = rep2[ro]; a21 = rep2[TS+ro]; a22 = rep2[2*TS+ro]; }
        if (m > 3) { size_t ro = (size_t)__float_as_int(e3.w)*(D_/2) + lane;
                    a30 = rep2[ro]; a31 = rep2[TS+ro]; a32 = rep2[2*TS+ro]; }

        ax += e0.x*a00.x + e0.y*a01.x + e0.z*a02.x;
        ay += e0.x*a00.y + e0.y*a01.y + e0.z*a02.y;
        if (m > 1) { ax += e1.x*a10.x + e1.y*a11.x + e1.z*a12.x;
                     ay += e1.x*a10.y + e1.y*a11.y + e1.z*a12.y; }
        if (m > 2) { ax += e2.x*a20.x + e2.y*a21.x + e2.z*a22.x;
                     ay += e2.x*a20.y + e2.y*a21.y + e2.z*a22.y; }
        if (m > 3) { ax += e3.x*a30.x + e3.y*a31.x + e3.z*a32.x;
                     ay += e3.x*a30.y + e3.y*a31.y + e3.z*a32.y; }
    }

    ax *= INV_SQRT_NN;
    ay *= INV_SQRT_NN;

    f32x2 v; v.x = ax; v.y = ay;
    __builtin_nontemporal_store(v, (f32x2*)(probes) + (size_t)p*(D_/2) + lane);

    float ov = ax*w_out[2*lane] + ay*w_out[2*lane+1];
    #pragma unroll
    for (int off = 32; off > 0; off >>= 1) ov += __shfl_down(ov, off);
    if (lane == 0) out[p] = ov;
}

extern "C" void kernel_launch(void* const* d_in, const int* in_sizes, int n_in,
                              void* d_out, int out_size, void* d_ws, size_t ws_size,
                              hipStream_t stream) {
    const float* atom_xyz  = (const float*)d_in[0];
    const float* probe_xyz = (const float*)d_in[1];
    const int*   probe_edges = (const int*)d_in[2];
    const float* ped       = (const float*)d_in[3];
    const float* cell      = (const float*)d_in[4];
    const float* atom_rep  = (const float*)d_in[8];
    const float* w1        = (const float*)d_in[9];
    const float* w2        = (const float*)d_in[10];
    const float* w_out     = (const float*)d_in[11];

    float* out    = (float*)d_out;        // 200000 floats (B,NP)
    float* probes = out + P_TOT;          // 200000*128 floats

    float4* edge4 = (float4*)d_ws;                      // E_TOT (16B-aligned first)
    float*  ftab  = (float*)(edge4 + E_TOT);            // GRID_N*FSTR
    int* counts   = (int*)(ftab + (size_t)GRID_N*FSTR); // P_TOT
    int* counts2  = counts + P_TOT;                     // P_TOT
    int* starts   = counts2 + P_TOT;                    // P_TOT
    int* bsums    = starts + P_TOT;                     // 256

    hipMemsetAsync(counts, 0, 2*P_TOT*sizeof(int), stream);  // counts + counts2

    build_table_kernel<<<(T_*GRID_N + 255)/256, 256, 0, stream>>>(w1, w2, ftab);

    count_kernel<<<(E_TOT + 255)/256, 256, 0, stream>>>(probe_edges, counts);

    scan1_kernel<<<SCAN_NBLK, 256, 0, stream>>>(counts, starts, bsums);
    scan2_kernel<<<1, 256, 0, stream>>>(bsums, SCAN_NBLK);
    scan3_kernel<<<SCAN_NBLK, 256, 0, stream>>>(starts, bsums);

    edge_scatter_kernel<<<(E_TOT + 255)/256, 256, 0, stream>>>(
        atom_xyz, probe_xyz, probe_edges, ped, cell, ftab,
        starts, counts2, edge4);

    gather_kernel<<<P_TOT/4, 256, 0, stream>>>(
        counts, starts, edge4, atom_rep, w_out, out, probes);
}

// Round 7
// 279.596 us; speedup vs baseline: 1.6349x; 1.0948x over previous
//
#include <hip/hip_runtime.h>
#include <math.h>

#define B_ 4
#define NA 1250
#define NP 50000
#define NE 125000
#define T_ 3
#define D_ 128
#define SHD 16
#define NB 10
#define HID 100
#define E_TOT (B_*NE)      // 500000
#define P_TOT (B_*NP)      // 200000
#define A_TOT (B_*NA)      // 5000
#define INV_SQRT_NN 0.22360679774997896f  // 1/sqrt(20)
#define SCAN_NBLK ((P_TOT + 1023) / 1024) // 196

#define GRID_N 8192
#define RMAX 24.0f
#define FSTR (T_*SHD)      // 48 floats per table row

typedef float f32x4 __attribute__((ext_vector_type(4)));

// ---------------- build radial table (wave-per-(t,ri), lane-parallel over j) --------
// ftab[ri][t*16+k] = f_{t,k}(r_i) = (silu(rb(r_i) @ W1_t) @ W2_t)_k
__global__ __launch_bounds__(256) void build_table_kernel(
    const float* __restrict__ w1, const float* __restrict__ w2,
    float* __restrict__ ftab)
{
    int gid  = blockIdx.x*256 + threadIdx.x;
    int w    = gid >> 6;            // wave id: 0 .. T_*GRID_N-1
    int lane = gid & 63;
    int t  = w >> 13;               // / GRID_N
    int ri = w & (GRID_N-1);

    float r = (float)ri * (RMAX / (float)(GRID_N-1));
    float rb[NB];
    float rs = r * (9.0f / 4.0f);
    #pragma unroll
    for (int i = 0; i < NB; ++i) {
        float dif = rs - (float)i;
        rb[i] = __expf(-dif*dif) * 1.12f;
    }

    float fk[SHD];
    #pragma unroll
    for (int k = 0; k < SHD; ++k) fk[k] = 0.0f;

    if (lane < 50) {
        #pragma unroll
        for (int jj = 0; jj < 2; ++jj) {
            int j = lane + jj*50;
            float h = 0.0f;
            #pragma unroll
            for (int i = 0; i < NB; ++i)
                h += rb[i] * w1[(size_t)(t*NB + i)*HID + j];   // coalesced across lanes
            float s = h / (1.0f + __expf(-h));                 // silu
            const float* c2 = w2 + (size_t)(t*HID + j)*SHD;    // 16 contiguous
            #pragma unroll
            for (int k = 0; k < SHD; ++k) fk[k] += s * c2[k];
        }
    }

    // butterfly reduce each of the 16 accumulators across the wave
    #pragma unroll
    for (int mask = 1; mask < 64; mask <<= 1) {
        #pragma unroll
        for (int k = 0; k < SHD; ++k) fk[k] += __shfl_xor(fk[k], mask);
    }

    if (lane == 0) {
        float* dstp = ftab + (size_t)ri*FSTR + t*SHD;  // 64B-aligned
        #pragma unroll
        for (int k = 0; k < SHD; ++k) dstp[k] = fk[k];
    }
}

// ---------------- count: histogram of dst + per-edge rank ----------------
__global__ __launch_bounds__(256) void count_kernel(const int* __restrict__ probe_edges,
                                                    int* __restrict__ counts,
                                                    int* __restrict__ rank)
{
    int e = blockIdx.x*256 + threadIdx.x;
    if (e >= E_TOT) return;
    int b = e / NE;
    int2 pe = ((const int2*)probe_edges)[e];
    int dst = pe.y + b*NP;
    rank[e] = atomicAdd(&counts[dst], 1);
}

// ---------------- scan kernels (counting-sort CSR) ----------------
__global__ __launch_bounds__(256) void scan1_kernel(const int* __restrict__ counts,
                                                    int* __restrict__ starts,
                                                    int* __restrict__ bsums)
{
    __shared__ int sd[256];
    int base = blockIdx.x*1024 + threadIdx.x*4;
    int v0 = (base+0 < P_TOT) ? counts[base+0] : 0;
    int v1 = (base+1 < P_TOT) ? counts[base+1] : 0;
    int v2 = (base+2 < P_TOT) ? counts[base+2] : 0;
    int v3 = (base+3 < P_TOT) ? counts[base+3] : 0;
    int s = v0+v1+v2+v3;
    sd[threadIdx.x] = s;
    __syncthreads();
    for (int off = 1; off < 256; off <<= 1) {
        int t = (threadIdx.x >= off) ? sd[threadIdx.x - off] : 0;
        __syncthreads();
        sd[threadIdx.x] += t;
        __syncthreads();
    }
    int excl = sd[threadIdx.x] - s;
    if (base+0 < P_TOT) starts[base+0] = excl;
    if (base+1 < P_TOT) starts[base+1] = excl + v0;
    if (base+2 < P_TOT) starts[base+2] = excl + v0 + v1;
    if (base+3 < P_TOT) starts[base+3] = excl + v0 + v1 + v2;
    if (threadIdx.x == 255) bsums[blockIdx.x] = sd[255];
}

__global__ __launch_bounds__(256) void scan2_kernel(int* __restrict__ bsums, int n)
{
    __shared__ int sd[256];
    int s = (threadIdx.x < n) ? bsums[threadIdx.x] : 0;
    sd[threadIdx.x] = s;
    __syncthreads();
    for (int off = 1; off < 256; off <<= 1) {
        int t = (threadIdx.x >= off) ? sd[threadIdx.x - off] : 0;
        __syncthreads();
        sd[threadIdx.x] += t;
        __syncthreads();
    }
    if (threadIdx.x < n) bsums[threadIdx.x] = sd[threadIdx.x] - s;
}

__global__ __launch_bounds__(256) void scan3_kernel(int* __restrict__ starts,
                                                    const int* __restrict__ bsums)
{
    int add = bsums[blockIdx.x];
    int base = blockIdx.x*1024 + threadIdx.x*4;
    #pragma unroll
    for (int k = 0; k < 4; ++k)
        if (base+k < P_TOT) starts[base+k] += add;
}

// ---------------- edge_scatter: geometry + SH + interp -> CSR slot {s0,s1,s2,src} ----
__global__ __launch_bounds__(256) void edge_scatter_kernel(
    const float* __restrict__ atom_xyz, const float* __restrict__ probe_xyz,
    const int* __restrict__ probe_edges, const float* __restrict__ ped,
    const float* __restrict__ cell, const float* __restrict__ ftab,
    const int* __restrict__ starts, const int* __restrict__ rank,
    float4* __restrict__ edge4)
{
    int e = blockIdx.x * 256 + threadIdx.x;
    if (e >= E_TOT) return;
    int b  = e / NE;

    int2 pe = ((const int2*)probe_edges)[e];
    int src = pe.x + b * NA;
    int dst = pe.y + b * NP;

    float p0 = ped[(size_t)e*3 + 0];
    float p1 = ped[(size_t)e*3 + 1];
    float p2 = ped[(size_t)e*3 + 2];
    const float* cb = cell + b*9;
    float dx = p0*cb[0] + p1*cb[3] + p2*cb[6];
    float dy = p0*cb[1] + p1*cb[4] + p2*cb[7];
    float dz = p0*cb[2] + p1*cb[5] + p2*cb[8];

    float vx = probe_xyz[(size_t)dst*3+0] - (atom_xyz[(size_t)src*3+0] + dx);
    float vy = probe_xyz[(size_t)dst*3+1] - (atom_xyz[(size_t)src*3+1] + dy);
    float vz = probe_xyz[(size_t)dst*3+2] - (atom_xyz[(size_t)src*3+2] + dz);
    float r = sqrtf(vx*vx + vy*vy + vz*vz);
    float rinv = 1.0f / fmaxf(r, 1e-9f);
    float x = vx*rinv, y = vy*rinv, z = vz*rinv;
    float x2 = x*x, y2 = y*y, z2 = z*z;

    const float S3  = 1.7320508075688772f;
    const float S15 = 3.872983346207417f;
    float sh[SHD];
    sh[0]  = 1.0f;
    sh[1]  = S3 * x;
    sh[2]  = S3 * y;
    sh[3]  = S3 * z;
    sh[4]  = S15 * x * y;
    sh[5]  = S15 * y * z;
    sh[6]  = 1.118033988749895f * (3.0f*z2 - 1.0f);
    sh[7]  = S15 * x * z;
    sh[8]  = 1.9364916731037085f * (x2 - y2);
    sh[9]  = 2.091650066335189f  * y * (3.0f*x2 - y2);
    sh[10] = 10.246950765959598f * x * y * z;
    sh[11] = 1.6201851746019651f * y * (5.0f*z2 - 1.0f);
    sh[12] = 1.3228756555322954f * (5.0f*z2*z - 3.0f*z);
    sh[13] = 1.6201851746019651f * x * (5.0f*z2 - 1.0f);
    sh[14] = 5.123475382979799f  * z * (x2 - y2);
    sh[15] = 2.091650066335189f  * x * (x2 - 3.0f*y2);

    // table interpolation
    float u = r * ((float)(GRID_N-1) / RMAX);
    int i0 = (int)u;
    i0 = (i0 > GRID_N-2) ? (GRID_N-2) : i0;
    float w = u - (float)i0;
    const float* F0 = ftab + (size_t)i0 * FSTR;
    const float* F1 = F0 + FSTR;

    float sc[T_];
    #pragma unroll
    for (int t = 0; t < T_; ++t) {
        float d0 = 0.0f, d1 = 0.0f;
        #pragma unroll
        for (int k = 0; k < SHD; ++k) {
            d0 += F0[t*SHD + k] * sh[k];
            d1 += F1[t*SHD + k] * sh[k];
        }
        sc[t] = d0 + w * (d1 - d0);
    }

    int pos = starts[dst] + rank[e];
    edge4[pos] = make_float4(sc[0], sc[1], sc[2], __int_as_float(src));
}

// ---------------- gather: 2 probes/wave (32 lanes x float4), fused projection -------
__global__ __launch_bounds__(256) void gather_kernel(
    const int* __restrict__ counts, const int* __restrict__ starts,
    const float4* __restrict__ edge4, const float* __restrict__ atom_rep,
    const float* __restrict__ w_out,
    float* __restrict__ out, float* __restrict__ probes)
{
    int lane = threadIdx.x & 63;
    int half = lane >> 5;          // 0/1: which probe within the wave
    int l    = lane & 31;          // dim-group: handles dims 4l..4l+3
    int wv   = threadIdx.x >> 6;
    int p = blockIdx.x*8 + wv*2 + half;   // P_TOT divisible by 8

    int st  = starts[p];
    int cnt = counts[p];

    const float4* rep4 = (const float4*)atom_rep;  // 32 float4 per row
    const size_t TS = (size_t)A_TOT * (D_/4);      // float4 elems per t-slab

    float ax = 0.0f, ay = 0.0f, az = 0.0f, aw = 0.0f;

    for (int base = 0; base < cnt; base += 2) {
        int m = cnt - base;
        float4 e0, e1;
        e0 = edge4[st+base];
        if (m > 1) e1 = edge4[st+base+1];

        float4 a00,a01,a02, a10,a11,a12;
        {           size_t ro = (size_t)__float_as_int(e0.w)*(D_/4) + l;
                    a00 = rep4[ro]; a01 = rep4[TS+ro]; a02 = rep4[2*TS+ro]; }
        if (m > 1) { size_t ro = (size_t)__float_as_int(e1.w)*(D_/4) + l;
                    a10 = rep4[ro]; a11 = rep4[TS+ro]; a12 = rep4[2*TS+ro]; }

        ax += e0.x*a00.x + e0.y*a01.x + e0.z*a02.x;
        ay += e0.x*a00.y + e0.y*a01.y + e0.z*a02.y;
        az += e0.x*a00.z + e0.y*a01.z + e0.z*a02.z;
        aw += e0.x*a00.w + e0.y*a01.w + e0.z*a02.w;
        if (m > 1) {
            ax += e1.x*a10.x + e1.y*a11.x + e1.z*a12.x;
            ay += e1.x*a10.y + e1.y*a11.y + e1.z*a12.y;
            az += e1.x*a10.z + e1.y*a11.z + e1.z*a12.z;
            aw += e1.x*a10.w + e1.y*a11.w + e1.z*a12.w;
        }
    }

    ax *= INV_SQRT_NN; ay *= INV_SQRT_NN; az *= INV_SQRT_NN; aw *= INV_SQRT_NN;

    f32x4 v; v.x = ax; v.y = ay; v.z = az; v.w = aw;
    __builtin_nontemporal_store(v, (f32x4*)(probes) + (size_t)p*(D_/4) + l);

    float4 wo = ((const float4*)w_out)[l];
    float ov = ax*wo.x + ay*wo.y + az*wo.z + aw*wo.w;
    #pragma unroll
    for (int off = 16; off > 0; off >>= 1) ov += __shfl_down(ov, off, 32);
    if (l == 0) out[p] = ov;
}

extern "C" void kernel_launch(void* const* d_in, const int* in_sizes, int n_in,
                              void* d_out, int out_size, void* d_ws, size_t ws_size,
                              hipStream_t stream) {
    const float* atom_xyz  = (const float*)d_in[0];
    const float* probe_xyz = (const float*)d_in[1];
    const int*   probe_edges = (const int*)d_in[2];
    const float* ped       = (const float*)d_in[3];
    const float* cell      = (const float*)d_in[4];
    const float* atom_rep  = (const float*)d_in[8];
    const float* w1        = (const float*)d_in[9];
    const float* w2        = (const float*)d_in[10];
    const float* w_out     = (const float*)d_in[11];

    float* out    = (float*)d_out;        // 200000 floats (B,NP)
    float* probes = out + P_TOT;          // 200000*128 floats

    float4* edge4 = (float4*)d_ws;                      // E_TOT (16B-aligned first)
    float*  ftab  = (float*)(edge4 + E_TOT);            // GRID_N*FSTR
    int* counts   = (int*)(ftab + (size_t)GRID_N*FSTR); // P_TOT
    int* starts   = counts + P_TOT;                     // P_TOT
    int* bsums    = starts + P_TOT;                     // 256
    int* rank     = bsums + 256;                        // E_TOT

    hipMemsetAsync(counts, 0, P_TOT*sizeof(int), stream);

    build_table_kernel<<<(T_*GRID_N)/4, 256, 0, stream>>>(w1, w2, ftab);

    count_kernel<<<(E_TOT + 255)/256, 256, 0, stream>>>(probe_edges, counts, rank);

    scan1_kernel<<<SCAN_NBLK, 256, 0, stream>>>(counts, starts, bsums);
    scan2_kernel<<<1, 256, 0, stream>>>(bsums, SCAN_NBLK);
    scan3_kernel<<<SCAN_NBLK, 256, 0, stream>>>(starts, bsums);

    edge_scatter_kernel<<<(E_TOT + 255)/256, 256, 0, stream>>>(
        atom_xyz, probe_xyz, probe_edges, ped, cell, ftab,
        starts, rank, edge4);

    gather_kernel<<<P_TOT/8, 256, 0, stream>>>(
        counts, starts, edge4, atom_rep, w_out, out, probes);
}

// Round 8
// 275.772 us; speedup vs baseline: 1.6576x; 1.0139x over previous
//
#include <hip/hip_runtime.h>
#include <math.h>

#define B_ 4
#define NA 1250
#define NP 50000
#define NE 125000
#define T_ 3
#define D_ 128
#define SHD 16
#define NB 10
#define HID 100
#define E_TOT (B_*NE)      // 500000
#define P_TOT (B_*NP)      // 200000
#define A_TOT (B_*NA)      // 5000
#define INV_SQRT_NN 0.22360679774997896f  // 1/sqrt(20)
#define SCAN_NBLK ((P_TOT + 1023) / 1024) // 196

#define GRID_N 8192
#define RMAX 24.0f
#define FSTR (T_*SHD)      // 48 floats per table row

#define NXCD 8
// gather grid: P_TOT/8 blocks = 25000, divisible by 8
#define GNW (P_TOT/8)      // 25000
#define GQ  (GNW/NXCD)     // 3125
// edge grid: 1954 blocks, 1954 = 8*244 + 2
#define ENW ((E_TOT + 255)/256)  // 1954
#define EQ  (ENW/NXCD)           // 244
#define ER  (ENW%NXCD)           // 2

typedef float f32x4 __attribute__((ext_vector_type(4)));

// bijective XCD swizzle for grids not divisible by 8 (m204 variant)
__device__ __forceinline__ int exed_swz(int bid) {
    int xcd = bid & 7, idx = bid >> 3;
    return (xcd < ER) ? xcd*(EQ+1) + idx
                      : ER*(EQ+1) + (xcd-ER)*EQ + idx;
}

// ---------------- build radial table (wave-per-(t,ri), lane-parallel over j) --------
// ftab[ri][t*16+k] = f_{t,k}(r_i) = (silu(rb(r_i) @ W1_t) @ W2_t)_k
__global__ __launch_bounds__(256) void build_table_kernel(
    const float* __restrict__ w1, const float* __restrict__ w2,
    float* __restrict__ ftab)
{
    int gid  = blockIdx.x*256 + threadIdx.x;
    int w    = gid >> 6;            // wave id: 0 .. T_*GRID_N-1
    int lane = gid & 63;
    int t  = w >> 13;               // / GRID_N
    int ri = w & (GRID_N-1);

    float r = (float)ri * (RMAX / (float)(GRID_N-1));
    float rb[NB];
    float rs = r * (9.0f / 4.0f);
    #pragma unroll
    for (int i = 0; i < NB; ++i) {
        float dif = rs - (float)i;
        rb[i] = __expf(-dif*dif) * 1.12f;
    }

    float fk[SHD];
    #pragma unroll
    for (int k = 0; k < SHD; ++k) fk[k] = 0.0f;

    if (lane < 50) {
        #pragma unroll
        for (int jj = 0; jj < 2; ++jj) {
            int j = lane + jj*50;
            float h = 0.0f;
            #pragma unroll
            for (int i = 0; i < NB; ++i)
                h += rb[i] * w1[(size_t)(t*NB + i)*HID + j];   // coalesced across lanes
            float s = h / (1.0f + __expf(-h));                 // silu
            const float* c2 = w2 + (size_t)(t*HID + j)*SHD;    // 16 contiguous
            #pragma unroll
            for (int k = 0; k < SHD; ++k) fk[k] += s * c2[k];
        }
    }

    // butterfly reduce each of the 16 accumulators across the wave
    #pragma unroll
    for (int mask = 1; mask < 64; mask <<= 1) {
        #pragma unroll
        for (int k = 0; k < SHD; ++k) fk[k] += __shfl_xor(fk[k], mask);
    }

    if (lane == 0) {
        float* dstp = ftab + (size_t)ri*FSTR + t*SHD;  // 64B-aligned
        #pragma unroll
        for (int k = 0; k < SHD; ++k) dstp[k] = fk[k];
    }
}

// ---------------- count: histogram of dst + per-edge rank ----------------
__global__ __launch_bounds__(256) void count_kernel(const int* __restrict__ probe_edges,
                                                    int* __restrict__ counts,
                                                    int* __restrict__ rank)
{
    int e = exed_swz(blockIdx.x)*256 + threadIdx.x;
    if (e >= E_TOT) return;
    int b = e / NE;
    int2 pe = ((const int2*)probe_edges)[e];
    int dst = pe.y + b*NP;
    rank[e] = atomicAdd(&counts[dst], 1);
}

// ---------------- scan kernels (counting-sort CSR) ----------------
__global__ __launch_bounds__(256) void scan1_kernel(const int* __restrict__ counts,
                                                    int* __restrict__ starts,
                                                    int* __restrict__ bsums)
{
    __shared__ int sd[256];
    int base = blockIdx.x*1024 + threadIdx.x*4;
    int v0 = (base+0 < P_TOT) ? counts[base+0] : 0;
    int v1 = (base+1 < P_TOT) ? counts[base+1] : 0;
    int v2 = (base+2 < P_TOT) ? counts[base+2] : 0;
    int v3 = (base+3 < P_TOT) ? counts[base+3] : 0;
    int s = v0+v1+v2+v3;
    sd[threadIdx.x] = s;
    __syncthreads();
    for (int off = 1; off < 256; off <<= 1) {
        int t = (threadIdx.x >= off) ? sd[threadIdx.x - off] : 0;
        __syncthreads();
        sd[threadIdx.x] += t;
        __syncthreads();
    }
    int excl = sd[threadIdx.x] - s;
    if (base+0 < P_TOT) starts[base+0] = excl;
    if (base+1 < P_TOT) starts[base+1] = excl + v0;
    if (base+2 < P_TOT) starts[base+2] = excl + v0 + v1;
    if (base+3 < P_TOT) starts[base+3] = excl + v0 + v1 + v2;
    if (threadIdx.x == 255) bsums[blockIdx.x] = sd[255];
}

__global__ __launch_bounds__(256) void scan2_kernel(int* __restrict__ bsums, int n)
{
    __shared__ int sd[256];
    int s = (threadIdx.x < n) ? bsums[threadIdx.x] : 0;
    sd[threadIdx.x] = s;
    __syncthreads();
    for (int off = 1; off < 256; off <<= 1) {
        int t = (threadIdx.x >= off) ? sd[threadIdx.x - off] : 0;
        __syncthreads();
        sd[threadIdx.x] += t;
        __syncthreads();
    }
    if (threadIdx.x < n) bsums[threadIdx.x] = sd[threadIdx.x] - s;
}

__global__ __launch_bounds__(256) void scan3_kernel(int* __restrict__ starts,
                                                    const int* __restrict__ bsums)
{
    int add = bsums[blockIdx.x];
    int base = blockIdx.x*1024 + threadIdx.x*4;
    #pragma unroll
    for (int k = 0; k < 4; ++k)
        if (base+k < P_TOT) starts[base+k] += add;
}

// ---------------- edge_scatter: geometry + SH + interp -> CSR slot {s0,s1,s2,src} ----
__global__ __launch_bounds__(256) void edge_scatter_kernel(
    const float* __restrict__ atom_xyz, const float* __restrict__ probe_xyz,
    const int* __restrict__ probe_edges, const float* __restrict__ ped,
    const float* __restrict__ cell, const float* __restrict__ ftab,
    const int* __restrict__ starts, const int* __restrict__ rank,
    float4* __restrict__ edge4)
{
    int e = exed_swz(blockIdx.x)*256 + threadIdx.x;
    if (e >= E_TOT) return;
    int b  = e / NE;

    int2 pe = ((const int2*)probe_edges)[e];
    int src = pe.x + b * NA;
    int dst = pe.y + b * NP;

    float p0 = __builtin_nontemporal_load(ped + (size_t)e*3 + 0);
    float p1 = __builtin_nontemporal_load(ped + (size_t)e*3 + 1);
    float p2 = __builtin_nontemporal_load(ped + (size_t)e*3 + 2);
    const float* cb = cell + b*9;
    float dx = p0*cb[0] + p1*cb[3] + p2*cb[6];
    float dy = p0*cb[1] + p1*cb[4] + p2*cb[7];
    float dz = p0*cb[2] + p1*cb[5] + p2*cb[8];

    float vx = probe_xyz[(size_t)dst*3+0] - (atom_xyz[(size_t)src*3+0] + dx);
    float vy = probe_xyz[(size_t)dst*3+1] - (atom_xyz[(size_t)src*3+1] + dy);
    float vz = probe_xyz[(size_t)dst*3+2] - (atom_xyz[(size_t)src*3+2] + dz);
    float r = sqrtf(vx*vx + vy*vy + vz*vz);
    float rinv = 1.0f / fmaxf(r, 1e-9f);
    float x = vx*rinv, y = vy*rinv, z = vz*rinv;
    float x2 = x*x, y2 = y*y, z2 = z*z;

    const float S3  = 1.7320508075688772f;
    const float S15 = 3.872983346207417f;
    float sh[SHD];
    sh[0]  = 1.0f;
    sh[1]  = S3 * x;
    sh[2]  = S3 * y;
    sh[3]  = S3 * z;
    sh[4]  = S15 * x * y;
    sh[5]  = S15 * y * z;
    sh[6]  = 1.118033988749895f * (3.0f*z2 - 1.0f);
    sh[7]  = S15 * x * z;
    sh[8]  = 1.9364916731037085f * (x2 - y2);
    sh[9]  = 2.091650066335189f  * y * (3.0f*x2 - y2);
    sh[10] = 10.246950765959598f * x * y * z;
    sh[11] = 1.6201851746019651f * y * (5.0f*z2 - 1.0f);
    sh[12] = 1.3228756555322954f * (5.0f*z2*z - 3.0f*z);
    sh[13] = 1.6201851746019651f * x * (5.0f*z2 - 1.0f);
    sh[14] = 5.123475382979799f  * z * (x2 - y2);
    sh[15] = 2.091650066335189f  * x * (x2 - 3.0f*y2);

    // table interpolation
    float u = r * ((float)(GRID_N-1) / RMAX);
    int i0 = (int)u;
    i0 = (i0 > GRID_N-2) ? (GRID_N-2) : i0;
    float w = u - (float)i0;
    const float* F0 = ftab + (size_t)i0 * FSTR;
    const float* F1 = F0 + FSTR;

    float sc[T_];
    #pragma unroll
    for (int t = 0; t < T_; ++t) {
        float d0 = 0.0f, d1 = 0.0f;
        #pragma unroll
        for (int k = 0; k < SHD; ++k) {
            d0 += F0[t*SHD + k] * sh[k];
            d1 += F1[t*SHD + k] * sh[k];
        }
        sc[t] = d0 + w * (d1 - d0);
    }

    int pos = starts[dst] + rank[e];
    edge4[pos] = make_float4(sc[0], sc[1], sc[2], __int_as_float(src));
}

// ---------------- gather: 2 probes/wave (32 lanes x float4), XCD-swizzled ----------
__global__ __launch_bounds__(256) void gather_kernel(
    const int* __restrict__ counts, const int* __restrict__ starts,
    const float4* __restrict__ edge4, const float* __restrict__ atom_rep,
    const float* __restrict__ w_out,
    float* __restrict__ out, float* __restrict__ probes)
{
    int lane = threadIdx.x & 63;
    int half = lane >> 5;          // 0/1: which probe within the wave
    int l    = lane & 31;          // dim-group: handles dims 4l..4l+3
    int wv   = threadIdx.x >> 6;
    // XCD swizzle: GNW % 8 == 0, each XCD gets a contiguous chunk of 3125 blocks
    int blk = (blockIdx.x & 7)*GQ + (blockIdx.x >> 3);
    int p = blk*8 + wv*2 + half;

    int st  = starts[p];
    int cnt = counts[p];

    const float4* rep4 = (const float4*)atom_rep;  // 32 float4 per row
    const size_t TS = (size_t)A_TOT * (D_/4);      // float4 elems per t-slab

    float ax = 0.0f, ay = 0.0f, az = 0.0f, aw = 0.0f;

    for (int base = 0; base < cnt; base += 2) {
        int m = cnt - base;
        float4 e0, e1;
        e0 = edge4[st+base];
        if (m > 1) e1 = edge4[st+base+1];

        float4 a00,a01,a02, a10,a11,a12;
        {           size_t ro = (size_t)__float_as_int(e0.w)*(D_/4) + l;
                    a00 = rep4[ro]; a01 = rep4[TS+ro]; a02 = rep4[2*TS+ro]; }
        if (m > 1) { size_t ro = (size_t)__float_as_int(e1.w)*(D_/4) + l;
                    a10 = rep4[ro]; a11 = rep4[TS+ro]; a12 = rep4[2*TS+ro]; }

        ax += e0.x*a00.x + e0.y*a01.x + e0.z*a02.x;
        ay += e0.x*a00.y + e0.y*a01.y + e0.z*a02.y;
        az += e0.x*a00.z + e0.y*a01.z + e0.z*a02.z;
        aw += e0.x*a00.w + e0.y*a01.w + e0.z*a02.w;
        if (m > 1) {
            ax += e1.x*a10.x + e1.y*a11.x + e1.z*a12.x;
            ay += e1.x*a10.y + e1.y*a11.y + e1.z*a12.y;
            az += e1.x*a10.z + e1.y*a11.z + e1.z*a12.z;
            aw += e1.x*a10.w + e1.y*a11.w + e1.z*a12.w;
        }
    }

    ax *= INV_SQRT_NN; ay *= INV_SQRT_NN; az *= INV_SQRT_NN; aw *= INV_SQRT_NN;

    f32x4 v; v.x = ax; v.y = ay; v.z = az; v.w = aw;
    __builtin_nontemporal_store(v, (f32x4*)(probes) + (size_t)p*(D_/4) + l);

    float4 wo = ((const float4*)w_out)[l];
    float ov = ax*wo.x + ay*wo.y + az*wo.z + aw*wo.w;
    #pragma unroll
    for (int off = 16; off > 0; off >>= 1) ov += __shfl_down(ov, off, 32);
    if (l == 0) out[p] = ov;
}

extern "C" void kernel_launch(void* const* d_in, const int* in_sizes, int n_in,
                              void* d_out, int out_size, void* d_ws, size_t ws_size,
                              hipStream_t stream) {
    const float* atom_xyz  = (const float*)d_in[0];
    const float* probe_xyz = (const float*)d_in[1];
    const int*   probe_edges = (const int*)d_in[2];
    const float* ped       = (const float*)d_in[3];
    const float* cell      = (const float*)d_in[4];
    const float* atom_rep  = (const float*)d_in[8];
    const float* w1        = (const float*)d_in[9];
    const float* w2        = (const float*)d_in[10];
    const float* w_out     = (const float*)d_in[11];

    float* out    = (float*)d_out;        // 200000 floats (B,NP)
    float* probes = out + P_TOT;          // 200000*128 floats

    float4* edge4 = (float4*)d_ws;                      // E_TOT (16B-aligned first)
    float*  ftab  = (float*)(edge4 + E_TOT);            // GRID_N*FSTR
    int* counts   = (int*)(ftab + (size_t)GRID_N*FSTR); // P_TOT
    int* starts   = counts + P_TOT;                     // P_TOT
    int* bsums    = starts + P_TOT;                     // 256
    int* rank     = bsums + 256;                        // E_TOT

    hipMemsetAsync(counts, 0, P_TOT*sizeof(int), stream);

    build_table_kernel<<<(T_*GRID_N)/4, 256, 0, stream>>>(w1, w2, ftab);

    count_kernel<<<ENW, 256, 0, stream>>>(probe_edges, counts, rank);

    scan1_kernel<<<SCAN_NBLK, 256, 0, stream>>>(counts, starts, bsums);
    scan2_kernel<<<1, 256, 0, stream>>>(bsums, SCAN_NBLK);
    scan3_kernel<<<SCAN_NBLK, 256, 0, stream>>>(starts, bsums);

    edge_scatter_kernel<<<ENW, 256, 0, stream>>>(
        atom_xyz, probe_xyz, probe_edges, ped, cell, ftab,
        starts, rank, edge4);

    gather_kernel<<<GNW, 256, 0, stream>>>(
        counts, starts, edge4, atom_rep, w_out, out, probes);
}

// Round 9
// 271.177 us; speedup vs baseline: 1.6857x; 1.0169x over previous
//
#include <hip/hip_runtime.h>
#include <math.h>

#define B_ 4
#define NA 1250
#define NP 50000
#define NE 125000
#define T_ 3
#define D_ 128
#define SHD 16
#define NB 10
#define HID 100
#define E_TOT (B_*NE)      // 500000
#define P_TOT (B_*NP)      // 200000
#define A_TOT (B_*NA)      // 5000
#define INV_SQRT_NN 0.22360679774997896f  // 1/sqrt(20)
#define SCAN_NBLK ((P_TOT + 1023) / 1024) // 196

#define GRID_N 8192
#define RMAX 24.0f
#define FSTR (T_*SHD)      // 48 floats per table row

#define NXCD 8
// edge grid: 1954 blocks, 1954 = 8*244 + 2
#define ENW ((E_TOT + 255)/256)  // 1954
#define EQ  (ENW/NXCD)           // 244
#define ER  (ENW%NXCD)           // 2
#define BT_BLOCKS ((T_*GRID_N)/4)  // 6144 build-table blocks (4 waves each)
// gather: grid-stride, 3200 blocks * 8 probe-slots = 25600 slots, 8 sweeps
#define GB 3200
#define GSLOTS (GB*8)

typedef float f32x4 __attribute__((ext_vector_type(4)));

// bijective XCD swizzle for the 1954-block edge grids (m204 variant)
__device__ __forceinline__ int exed_swz(int bid) {
    int xcd = bid & 7, idx = bid >> 3;
    return (xcd < ER) ? xcd*(EQ+1) + idx
                      : ER*(EQ+1) + (xcd-ER)*EQ + idx;
}

// ---------------- prep: build radial table  +  dst histogram/rank (fused) ----------
// blocks [0, BT_BLOCKS): ftab[ri][t*16+k] = (silu(rb(r_i)@W1_t)@W2_t)_k, wave-per-(t,ri)
// blocks [BT_BLOCKS, +ENW): rank[e] = atomicAdd(&counts[dst], 1)
__global__ __launch_bounds__(256) void prep_kernel(
    const float* __restrict__ w1, const float* __restrict__ w2,
    float* __restrict__ ftab,
    const int* __restrict__ probe_edges, int* __restrict__ counts,
    int* __restrict__ rank)
{
    if (blockIdx.x < BT_BLOCKS) {
        int gid  = blockIdx.x*256 + threadIdx.x;
        int w    = gid >> 6;            // wave id: 0 .. T_*GRID_N-1
        int lane = gid & 63;
        int t  = w >> 13;               // / GRID_N
        int ri = w & (GRID_N-1);

        float r = (float)ri * (RMAX / (float)(GRID_N-1));
        float rb[NB];
        float rs = r * (9.0f / 4.0f);
        #pragma unroll
        for (int i = 0; i < NB; ++i) {
            float dif = rs - (float)i;
            rb[i] = __expf(-dif*dif) * 1.12f;
        }

        float fk[SHD];
        #pragma unroll
        for (int k = 0; k < SHD; ++k) fk[k] = 0.0f;

        if (lane < 50) {
            #pragma unroll
            for (int jj = 0; jj < 2; ++jj) {
                int j = lane + jj*50;
                float h = 0.0f;
                #pragma unroll
                for (int i = 0; i < NB; ++i)
                    h += rb[i] * w1[(size_t)(t*NB + i)*HID + j];
                float s = h / (1.0f + __expf(-h));                 // silu
                const float* c2 = w2 + (size_t)(t*HID + j)*SHD;
                #pragma unroll
                for (int k = 0; k < SHD; ++k) fk[k] += s * c2[k];
            }
        }

        #pragma unroll
        for (int mask = 1; mask < 64; mask <<= 1) {
            #pragma unroll
            for (int k = 0; k < SHD; ++k) fk[k] += __shfl_xor(fk[k], mask);
        }

        if (lane == 0) {
            float* dstp = ftab + (size_t)ri*FSTR + t*SHD;
            #pragma unroll
            for (int k = 0; k < SHD; ++k) dstp[k] = fk[k];
        }
    } else {
        int e = exed_swz(blockIdx.x - BT_BLOCKS)*256 + threadIdx.x;
        if (e >= E_TOT) return;
        int b = e / NE;
        int2 pe = ((const int2*)probe_edges)[e];
        int dst = pe.y + b*NP;
        rank[e] = atomicAdd(&counts[dst], 1);
    }
}

// ---------------- scan kernels (counting-sort CSR; bsums applied by consumers) ------
__global__ __launch_bounds__(256) void scan1_kernel(const int* __restrict__ counts,
                                                    int* __restrict__ starts,
                                                    int* __restrict__ bsums)
{
    __shared__ int sd[256];
    int base = blockIdx.x*1024 + threadIdx.x*4;
    int v0 = (base+0 < P_TOT) ? counts[base+0] : 0;
    int v1 = (base+1 < P_TOT) ? counts[base+1] : 0;
    int v2 = (base+2 < P_TOT) ? counts[base+2] : 0;
    int v3 = (base+3 < P_TOT) ? counts[base+3] : 0;
    int s = v0+v1+v2+v3;
    sd[threadIdx.x] = s;
    __syncthreads();
    for (int off = 1; off < 256; off <<= 1) {
        int t = (threadIdx.x >= off) ? sd[threadIdx.x - off] : 0;
        __syncthreads();
        sd[threadIdx.x] += t;
        __syncthreads();
    }
    int excl = sd[threadIdx.x] - s;
    if (base+0 < P_TOT) starts[base+0] = excl;
    if (base+1 < P_TOT) starts[base+1] = excl + v0;
    if (base+2 < P_TOT) starts[base+2] = excl + v0 + v1;
    if (base+3 < P_TOT) starts[base+3] = excl + v0 + v1 + v2;
    if (threadIdx.x == 255) bsums[blockIdx.x] = sd[255];
}

__global__ __launch_bounds__(256) void scan2_kernel(int* __restrict__ bsums, int n)
{
    __shared__ int sd[256];
    int s = (threadIdx.x < n) ? bsums[threadIdx.x] : 0;
    sd[threadIdx.x] = s;
    __syncthreads();
    for (int off = 1; off < 256; off <<= 1) {
        int t = (threadIdx.x >= off) ? sd[threadIdx.x - off] : 0;
        __syncthreads();
        sd[threadIdx.x] += t;
        __syncthreads();
    }
    if (threadIdx.x < n) bsums[threadIdx.x] = sd[threadIdx.x] - s;
}

// ---------------- edge_scatter: geometry + SH + interp -> CSR slot {s0,s1,s2,src} ----
__global__ __launch_bounds__(256) void edge_scatter_kernel(
    const float* __restrict__ atom_xyz, const float* __restrict__ probe_xyz,
    const int* __restrict__ probe_edges, const float* __restrict__ ped,
    const float* __restrict__ cell, const float* __restrict__ ftab,
    const int* __restrict__ starts, const int* __restrict__ bsums,
    const int* __restrict__ rank, float4* __restrict__ edge4)
{
    int e = exed_swz(blockIdx.x)*256 + threadIdx.x;
    if (e >= E_TOT) return;
    int b  = e / NE;

    int2 pe = ((const int2*)probe_edges)[e];
    int src = pe.x + b * NA;
    int dst = pe.y + b * NP;

    // issue CSR-slot loads early (independent of geometry)
    int pos = starts[dst] + bsums[dst >> 10] + rank[e];

    float p0 = __builtin_nontemporal_load(ped + (size_t)e*3 + 0);
    float p1 = __builtin_nontemporal_load(ped + (size_t)e*3 + 1);
    float p2 = __builtin_nontemporal_load(ped + (size_t)e*3 + 2);
    const float* cb = cell + b*9;
    float dx = p0*cb[0] + p1*cb[3] + p2*cb[6];
    float dy = p0*cb[1] + p1*cb[4] + p2*cb[7];
    float dz = p0*cb[2] + p1*cb[5] + p2*cb[8];

    float vx = probe_xyz[(size_t)dst*3+0] - (atom_xyz[(size_t)src*3+0] + dx);
    float vy = probe_xyz[(size_t)dst*3+1] - (atom_xyz[(size_t)src*3+1] + dy);
    float vz = probe_xyz[(size_t)dst*3+2] - (atom_xyz[(size_t)src*3+2] + dz);
    float r = sqrtf(vx*vx + vy*vy + vz*vz);
    float rinv = 1.0f / fmaxf(r, 1e-9f);
    float x = vx*rinv, y = vy*rinv, z = vz*rinv;
    float x2 = x*x, y2 = y*y, z2 = z*z;

    const float S3  = 1.7320508075688772f;
    const float S15 = 3.872983346207417f;
    float sh[SHD];
    sh[0]  = 1.0f;
    sh[1]  = S3 * x;
    sh[2]  = S3 * y;
    sh[3]  = S3 * z;
    sh[4]  = S15 * x * y;
    sh[5]  = S15 * y * z;
    sh[6]  = 1.118033988749895f * (3.0f*z2 - 1.0f);
    sh[7]  = S15 * x * z;
    sh[8]  = 1.9364916731037085f * (x2 - y2);
    sh[9]  = 2.091650066335189f  * y * (3.0f*x2 - y2);
    sh[10] = 10.246950765959598f * x * y * z;
    sh[11] = 1.6201851746019651f * y * (5.0f*z2 - 1.0f);
    sh[12] = 1.3228756555322954f * (5.0f*z2*z - 3.0f*z);
    sh[13] = 1.6201851746019651f * x * (5.0f*z2 - 1.0f);
    sh[14] = 5.123475382979799f  * z * (x2 - y2);
    sh[15] = 2.091650066335189f  * x * (x2 - 3.0f*y2);

    // table interpolation
    float u = r * ((float)(GRID_N-1) / RMAX);
    int i0 = (int)u;
    i0 = (i0 > GRID_N-2) ? (GRID_N-2) : i0;
    float w = u - (float)i0;
    const float* F0 = ftab + (size_t)i0 * FSTR;
    const float* F1 = F0 + FSTR;

    float sc[T_];
    #pragma unroll
    for (int t = 0; t < T_; ++t) {
        float d0 = 0.0f, d1 = 0.0f;
        #pragma unroll
        for (int k = 0; k < SHD; ++k) {
            d0 += F0[t*SHD + k] * sh[k];
            d1 += F1[t*SHD + k] * sh[k];
        }
        sc[t] = d0 + w * (d1 - d0);
    }

    edge4[pos] = make_float4(sc[0], sc[1], sc[2], __int_as_float(src));
}

// ---------------- gather: grid-stride, software-pipelined across probes -------------
// 32 lanes per probe (float4/lane); next probe's st/cnt + first edge prefetched.
__global__ __launch_bounds__(256) void gather_kernel(
    const int* __restrict__ counts, const int* __restrict__ starts,
    const int* __restrict__ bsums,
    const float4* __restrict__ edge4, const float* __restrict__ atom_rep,
    const float* __restrict__ w_out,
    float* __restrict__ out, float* __restrict__ probes)
{
    int lane = threadIdx.x & 63;
    int half = lane >> 5;
    int l    = lane & 31;
    int wv   = threadIdx.x >> 6;
    int blk  = (blockIdx.x & 7)*(GB/8) + (blockIdx.x >> 3);   // GB % 8 == 0
    int p    = blk*8 + wv*2 + half;   // < GSLOTS <= P_TOT

    const float4* rep4 = (const float4*)atom_rep;
    const size_t TS = (size_t)A_TOT * (D_/4);
    float4 wo = ((const float4*)w_out)[l];

    int st  = starts[p] + bsums[p >> 10];
    int cnt = counts[p];
    float4 e0 = make_float4(0,0,0,0);
    if (cnt > 0) e0 = edge4[st];

    while (true) {
        int pn = p + GSLOTS;
        bool hasNext = (pn < P_TOT);
        int stn = 0, cntn = 0;
        if (hasNext) { stn = starts[pn] + bsums[pn >> 10]; cntn = counts[pn]; }

        float ax = 0.0f, ay = 0.0f, az = 0.0f, aw = 0.0f;
        if (cnt > 0) {
            size_t ro = (size_t)__float_as_int(e0.w)*(D_/4) + l;
            float4 a0 = rep4[ro], a1 = rep4[TS+ro], a2 = rep4[2*TS+ro];
            ax = e0.x*a0.x + e0.y*a1.x + e0.z*a2.x;
            ay = e0.x*a0.y + e0.y*a1.y + e0.z*a2.y;
            az = e0.x*a0.z + e0.y*a1.z + e0.z*a2.z;
            aw = e0.x*a0.w + e0.y*a1.w + e0.z*a2.w;
            for (int base = 1; base < cnt; base += 2) {
                int m = cnt - base;
                float4 f0 = edge4[st+base], f1 = f0;
                if (m > 1) f1 = edge4[st+base+1];
                float4 b00,b01,b02, b10,b11,b12;
                {           size_t r2 = (size_t)__float_as_int(f0.w)*(D_/4) + l;
                            b00 = rep4[r2]; b01 = rep4[TS+r2]; b02 = rep4[2*TS+r2]; }
                if (m > 1) { size_t r2 = (size_t)__float_as_int(f1.w)*(D_/4) + l;
                            b10 = rep4[r2]; b11 = rep4[TS+r2]; b12 = rep4[2*TS+r2]; }
                ax += f0.x*b00.x + f0.y*b01.x + f0.z*b02.x;
                ay += f0.x*b00.y + f0.y*b01.y + f0.z*b02.y;
                az += f0.x*b00.z + f0.y*b01.z + f0.z*b02.z;
                aw += f0.x*b00.w + f0.y*b01.w + f0.z*b02.w;
                if (m > 1) {
                    ax += f1.x*b10.x + f1.y*b11.x + f1.z*b12.x;
                    ay += f1.x*b10.y + f1.y*b11.y + f1.z*b12.y;
                    az += f1.x*b10.z + f1.y*b11.z + f1.z*b12.z;
                    aw += f1.x*b10.w + f1.y*b11.w + f1.z*b12.w;
                }
            }
        }

        // prefetch next probe's first edge while FMAs retire
        float4 e0n = make_float4(0,0,0,0);
        if (hasNext && cntn > 0) e0n = edge4[stn];

        ax *= INV_SQRT_NN; ay *= INV_SQRT_NN; az *= INV_SQRT_NN; aw *= INV_SQRT_NN;

        f32x4 v; v.x = ax; v.y = ay; v.z = az; v.w = aw;
        __builtin_nontemporal_store(v, (f32x4*)(probes) + (size_t)p*(D_/4) + l);

        float ov = ax*wo.x + ay*wo.y + az*wo.z + aw*wo.w;
        #pragma unroll
        for (int off = 16; off > 0; off >>= 1) ov += __shfl_down(ov, off, 32);
        if (l == 0) out[p] = ov;

        if (!hasNext) break;
        p = pn; st = stn; cnt = cntn; e0 = e0n;
    }
}

extern "C" void kernel_launch(void* const* d_in, const int* in_sizes, int n_in,
                              void* d_out, int out_size, void* d_ws, size_t ws_size,
                              hipStream_t stream) {
    const float* atom_xyz  = (const float*)d_in[0];
    const float* probe_xyz = (const float*)d_in[1];
    const int*   probe_edges = (const int*)d_in[2];
    const float* ped       = (const float*)d_in[3];
    const float* cell      = (const float*)d_in[4];
    const float* atom_rep  = (const float*)d_in[8];
    const float* w1        = (const float*)d_in[9];
    const float* w2        = (const float*)d_in[10];
    const float* w_out     = (const float*)d_in[11];

    float* out    = (float*)d_out;        // 200000 floats (B,NP)
    float* probes = out + P_TOT;          // 200000*128 floats

    float4* edge4 = (float4*)d_ws;                      // E_TOT (16B-aligned first)
    float*  ftab  = (float*)(edge4 + E_TOT);            // GRID_N*FSTR
    int* counts   = (int*)(ftab + (size_t)GRID_N*FSTR); // P_TOT
    int* starts   = counts + P_TOT;                     // P_TOT
    int* bsums    = starts + P_TOT;                     // 256
    int* rank     = bsums + 256;                        // E_TOT

    hipMemsetAsync(counts, 0, P_TOT*sizeof(int), stream);

    prep_kernel<<<BT_BLOCKS + ENW, 256, 0, stream>>>(
        w1, w2, ftab, probe_edges, counts, rank);

    scan1_kernel<<<SCAN_NBLK, 256, 0, stream>>>(counts, starts, bsums);
    scan2_kernel<<<1, 256, 0, stream>>>(bsums, SCAN_NBLK);

    edge_scatter_kernel<<<ENW, 256, 0, stream>>>(
        atom_xyz, probe_xyz, probe_edges, ped, cell, ftab,
        starts, bsums, rank, edge4);

    gather_kernel<<<GB, 256, 0, stream>>>(
        counts, starts, bsums, edge4, atom_rep, w_out, out, probes);
}